// Round 5
// baseline (894.486 us; speedup 1.0000x reference)
//
#include <hip/hip_runtime.h>

#define LEAK 0.2f

// ---------------- CSR build (incoming edges per dst) ----------------
__global__ void count_kernel(const int* __restrict__ dstp, int* __restrict__ cnt, int E) {
  int e = blockIdx.x * blockDim.x + threadIdx.x;
  if (e < E) atomicAdd(&cnt[dstp[e]], 1);
}

// Two-level scan, all coalesced.
__global__ __launch_bounds__(1024)
void scan_blocks(const int* __restrict__ cnt, int* __restrict__ tscan,
                 int* __restrict__ bsum, int n) {
  __shared__ int sh[1024];
  int t = threadIdx.x;
  int i = blockIdx.x * 1024 + t;
  sh[t] = (i < n) ? cnt[i] : 0;
  __syncthreads();
  for (int off = 1; off < 1024; off <<= 1) {
    int u = (t >= off) ? sh[t - off] : 0;
    __syncthreads();
    sh[t] += u;
    __syncthreads();
  }
  if (i < n) tscan[i] = sh[t];
  if (t == 1023) bsum[blockIdx.x] = sh[1023];
}

__global__ __launch_bounds__(1024)
void scan_bsums(int* __restrict__ bsum, int* __restrict__ rowptr, int nb, int n) {
  __shared__ int sh[1024];
  int t = threadIdx.x;
  sh[t] = (t < nb) ? bsum[t] : 0;
  __syncthreads();
  for (int off = 1; off < 1024; off <<= 1) {
    int u = (t >= off) ? sh[t - off] : 0;
    __syncthreads();
    sh[t] += u;
    __syncthreads();
  }
  if (t < nb) bsum[t] = sh[t];  // inclusive in place
  if (t == nb - 1) rowptr[n] = sh[t];
}

__global__ __launch_bounds__(1024)
void scan_final(const int* __restrict__ cnt, const int* __restrict__ tscan,
                const int* __restrict__ bsum, int* __restrict__ rowptr, int n) {
  int i = blockIdx.x * 1024 + threadIdx.x;
  if (i < n) {
    int bpref = (blockIdx.x == 0) ? 0 : bsum[blockIdx.x - 1];
    rowptr[i] = bpref + tscan[i] - cnt[i];
  }
}

__global__ void fill_kernel(const int* __restrict__ srcp, const int* __restrict__ dstp,
                            const int* __restrict__ rowptr, int* __restrict__ cur,
                            int* __restrict__ csr_src, int E) {
  int e = blockIdx.x * blockDim.x + threadIdx.x;
  if (e < E) {
    int d = dstp[e];
    int pos = atomicAdd(&cur[d], 1);
    csr_src[rowptr[d] + pos] = srcp[e];
  }
}

// ---------- GEMM: C[M,NOUT] = A[M,128] @ W[128,NOUT] + bias, optional ReLU ----------
// 128x128 block tile, 8x8 per-thread micro-tile (16x16 thread grid): 256 FMA per
// 8 ds_read_b128 + 8 global loads per k4-step (2x the FMA:mem ratio of the 4x8
// version). W staged in LDS in two 64-k chunks (32 KB) -> 4 blocks/CU. A-chunk
// footprint per block = 128 rows x 256 B = 32 KB = L1; 16 lanes broadcast each
// A address. In-place safe (C==A): block reads only rows it writes; chunk-end
// __syncthreads() fences all A reads before the C write.
template<int NOUT, bool RELU>
__global__ __launch_bounds__(256)
void gemm_k128(const float* __restrict__ A, const float* __restrict__ W,
               const float* __restrict__ bias, float* __restrict__ C, int M) {
  constexpr int TN = NOUT / 16;  // cols/thread: 8 (NOUT=128) or 4 (NOUT=64)
  constexpr int TM = 8;          // rows/thread
  constexpr int KC = 64;
  __shared__ float Ws[KC * NOUT];
  int tid = threadIdx.x;
  int rg = tid >> 4, cg = tid & 15;
  int row0 = blockIdx.x * 128;
  int r[TM];
#pragma unroll
  for (int i = 0; i < TM; ++i) { int rr = row0 + rg * TM + i; r[i] = rr < M ? rr : M - 1; }

  float acc[TM][TN];
#pragma unroll
  for (int i = 0; i < TM; ++i)
#pragma unroll
    for (int j = 0; j < TN; ++j) acc[i][j] = 0.f;

  for (int kc = 0; kc < 128; kc += KC) {
    for (int i = tid * 4; i < KC * NOUT; i += 256 * 4)
      *(float4*)&Ws[i] = *(const float4*)&W[kc * NOUT + i];
    __syncthreads();

#pragma unroll 2
    for (int k4 = 0; k4 < KC / 4; ++k4) {
      float4 a[TM];
#pragma unroll
      for (int i = 0; i < TM; ++i) a[i] = *(const float4*)&A[(size_t)r[i] * 128 + kc + k4 * 4];
#pragma unroll
      for (int kk = 0; kk < 4; ++kk) {
        float b[TN];
#pragma unroll
        for (int j4 = 0; j4 < TN / 4; ++j4)
          *(float4*)&b[j4 * 4] = *(const float4*)&Ws[(k4 * 4 + kk) * NOUT + cg * TN + j4 * 4];
#pragma unroll
        for (int i = 0; i < TM; ++i) {
          float av = ((const float*)&a[i])[kk];
#pragma unroll
          for (int j = 0; j < TN; ++j) acc[i][j] += av * b[j];
        }
      }
    }
    __syncthreads();  // fences A reads of this chunk; also before restage
  }

  float bv[TN];
#pragma unroll
  for (int j4 = 0; j4 < TN / 4; ++j4)
    *(float4*)&bv[j4 * 4] = *(const float4*)&bias[cg * TN + j4 * 4];

#pragma unroll
  for (int i = 0; i < TM; ++i) {
    int rr = row0 + rg * TM + i;
    if (rr < M) {
#pragma unroll
      for (int j4 = 0; j4 < TN / 4; ++j4) {
        float4 o;
        float* op = (float*)&o;
#pragma unroll
        for (int q = 0; q < 4; ++q) {
          float v = acc[i][j4 * 4 + q] + bv[j4 * 4 + q];
          if (RELU) v = fmaxf(v, 0.f);
          op[q] = v;
        }
        *(float4*)&C[(size_t)rr * NOUT + cg * TN + j4 * 4] = o;
      }
    }
  }
}

// ---------- GATv2 aggregation: one wave per node, 4 edges in flight ----------
template<int H>
__global__ __launch_bounds__(256)
void gat_agg(const float* __restrict__ xl, const float* __restrict__ xr,
             const float* __restrict__ skip, const float* __restrict__ att,
             const float* __restrict__ gbias, const int* __restrict__ rowptr,
             const int* __restrict__ csr_src, float* __restrict__ out,
             int n, int relu) {
  constexpr int C = 128 / H;  // channels per head
  constexpr int G = C / 2;    // lanes per head-group (2 floats/lane)
  int wid = blockIdx.x * (blockDim.x >> 6) + (threadIdx.x >> 6);
  if (wid >= n) return;
  int lane = threadIdx.x & 63;
  size_t base = (size_t)wid * 128 + lane * 2;
  float2 xrv = *(const float2*)(xr + base);
  float2 av = *(const float2*)(att + lane * 2);  // att flat [H*C]=[128]
  float2 acc = make_float2(0.f, 0.f);
  float denom = 0.f;
  int e0 = rowptr[wid], e1 = rowptr[wid + 1];

  // self-loop
  {
    float2 xlv = *(const float2*)(xl + base);
    float ex = xlv.x + xrv.x; ex = ex > 0.f ? ex : LEAK * ex;
    float ey = xlv.y + xrv.y; ey = ey > 0.f ? ey : LEAK * ey;
    float p = ex * av.x + ey * av.y;
#pragma unroll
    for (int o = 1; o < G; o <<= 1) p += __shfl_xor(p, o, 64);
    float w = __expf(p);
    denom += w;
    acc.x += w * xlv.x;
    acc.y += w * xlv.y;
  }

  int idx = e0;
  for (; idx + 4 <= e1; idx += 4) {
    int s0 = csr_src[idx], s1 = csr_src[idx + 1], s2 = csr_src[idx + 2], s3 = csr_src[idx + 3];
    float2 v0 = *(const float2*)(xl + (size_t)s0 * 128 + lane * 2);
    float2 v1 = *(const float2*)(xl + (size_t)s1 * 128 + lane * 2);
    float2 v2 = *(const float2*)(xl + (size_t)s2 * 128 + lane * 2);
    float2 v3 = *(const float2*)(xl + (size_t)s3 * 128 + lane * 2);
    float ex, ey;
    ex = v0.x + xrv.x; ex = ex > 0.f ? ex : LEAK * ex;
    ey = v0.y + xrv.y; ey = ey > 0.f ? ey : LEAK * ey;
    float p0 = ex * av.x + ey * av.y;
    ex = v1.x + xrv.x; ex = ex > 0.f ? ex : LEAK * ex;
    ey = v1.y + xrv.y; ey = ey > 0.f ? ey : LEAK * ey;
    float p1 = ex * av.x + ey * av.y;
    ex = v2.x + xrv.x; ex = ex > 0.f ? ex : LEAK * ex;
    ey = v2.y + xrv.y; ey = ey > 0.f ? ey : LEAK * ey;
    float p2 = ex * av.x + ey * av.y;
    ex = v3.x + xrv.x; ex = ex > 0.f ? ex : LEAK * ex;
    ey = v3.y + xrv.y; ey = ey > 0.f ? ey : LEAK * ey;
    float p3 = ex * av.x + ey * av.y;
#pragma unroll
    for (int o = 1; o < G; o <<= 1) {
      p0 += __shfl_xor(p0, o, 64);
      p1 += __shfl_xor(p1, o, 64);
      p2 += __shfl_xor(p2, o, 64);
      p3 += __shfl_xor(p3, o, 64);
    }
    float w0 = __expf(p0), w1 = __expf(p1), w2 = __expf(p2), w3 = __expf(p3);
    denom += (w0 + w1) + (w2 + w3);
    acc.x += w0 * v0.x + w1 * v1.x + w2 * v2.x + w3 * v3.x;
    acc.y += w0 * v0.y + w1 * v1.y + w2 * v2.y + w3 * v3.y;
  }
  for (; idx < e1; ++idx) {
    int src = csr_src[idx];
    float2 xlv = *(const float2*)(xl + (size_t)src * 128 + lane * 2);
    float ex = xlv.x + xrv.x; ex = ex > 0.f ? ex : LEAK * ex;
    float ey = xlv.y + xrv.y; ey = ey > 0.f ? ey : LEAK * ey;
    float p = ex * av.x + ey * av.y;
#pragma unroll
    for (int o = 1; o < G; o <<= 1) p += __shfl_xor(p, o, 64);
    float w = __expf(p);
    denom += w;
    acc.x += w * xlv.x;
    acc.y += w * xlv.y;
  }

  float inv = 1.f / denom;
  float2 sk = *(const float2*)(skip + base);
  float2 gb = *(const float2*)(gbias + lane * 2);
  float ox = acc.x * inv + gb.x + sk.x;
  float oy = acc.y * inv + gb.y + sk.y;
  if (relu) { ox = fmaxf(ox, 0.f); oy = fmaxf(oy, 0.f); }
  *(float2*)(out + base) = make_float2(ox, oy);
}

extern "C" void kernel_launch(void* const* d_in, const int* in_sizes, int n_in,
                              void* d_out, int out_size, void* d_ws, size_t ws_size,
                              hipStream_t stream) {
  const float* x       = (const float*)d_in[0];
  const int* ei        = (const int*)d_in[1];   // int32 (harness converts int64 -> int)
  const float* Wl1     = (const float*)d_in[2];
  const float* bl1     = (const float*)d_in[3];
  const float* Wr1     = (const float*)d_in[4];
  const float* br1     = (const float*)d_in[5];
  const float* att1    = (const float*)d_in[6];
  const float* b1      = (const float*)d_in[7];
  const float* Wl2     = (const float*)d_in[8];
  const float* bl2     = (const float*)d_in[9];
  const float* Wr2     = (const float*)d_in[10];
  const float* br2     = (const float*)d_in[11];
  const float* att2    = (const float*)d_in[12];
  const float* b2      = (const float*)d_in[13];
  const float* skip1_w = (const float*)d_in[14];
  const float* skip1_b = (const float*)d_in[15];
  const float* skip2_w = (const float*)d_in[16];
  const float* skip2_b = (const float*)d_in[17];
  const float* mlp1_w  = (const float*)d_in[18];
  const float* mlp1_b  = (const float*)d_in[19];
  const float* mlp2_w  = (const float*)d_in[20];
  const float* mlp2_b  = (const float*)d_in[21];

  const int N = in_sizes[0] / 128;
  const int E = in_sizes[1] / 2;
  float* out = (float*)d_out;

  char* ws = (char*)d_ws;
  size_t off = 0;
  auto alloc = [&](size_t bytes) -> void* {
    void* p = ws + off;
    off = (off + bytes + 255) & ~(size_t)255;
    return p;
  };
  int* rowptr  = (int*)alloc((size_t)(N + 1) * sizeof(int));
  int* cnt     = (int*)alloc((size_t)N * sizeof(int));
  int* tscan   = (int*)alloc((size_t)N * sizeof(int));
  int* bsum    = (int*)alloc((size_t)1024 * sizeof(int));
  int* csr_src = (int*)alloc((size_t)E * sizeof(int));
  float* bufA  = (float*)alloc((size_t)N * 128 * sizeof(float));
  float* bufB  = (float*)alloc((size_t)N * 128 * sizeof(float));
  float* bufC  = (float*)alloc((size_t)N * 128 * sizeof(float));

  const int* srcp = ei;
  const int* dstp = ei + E;

  const int egrid = (E + 255) / 256;
  const int ggrid = (N + 127) / 128;
  const int agrid = (N + 3) / 4;
  const int nb = (N + 1023) / 1024;

  // CSR by dst (shared by both GAT layers)
  hipMemsetAsync(cnt, 0, (size_t)N * sizeof(int), stream);
  count_kernel<<<egrid, 256, 0, stream>>>(dstp, cnt, E);
  scan_blocks<<<nb, 1024, 0, stream>>>(cnt, tscan, bsum, N);
  scan_bsums<<<1, 1024, 0, stream>>>(bsum, rowptr, nb, N);
  scan_final<<<nb, 1024, 0, stream>>>(cnt, tscan, bsum, rowptr, N);
  hipMemsetAsync(cnt, 0, (size_t)N * sizeof(int), stream);
  fill_kernel<<<egrid, 256, 0, stream>>>(srcp, dstp, rowptr, cnt, csr_src, E);

  // ---- Layer 1: GATv2(128 -> 4x32 concat) + skip + ReLU ----
  gemm_k128<128, false><<<ggrid, 256, 0, stream>>>(x, Wl1, bl1, bufA, N);      // xl1
  gemm_k128<128, false><<<ggrid, 256, 0, stream>>>(x, Wr1, br1, bufB, N);      // xr1
  gemm_k128<128, false><<<ggrid, 256, 0, stream>>>(x, skip1_w, skip1_b, bufC, N); // skip1
  gat_agg<4><<<agrid, 256, 0, stream>>>(bufA, bufB, bufC, att1, b1,
                                        rowptr, csr_src, bufC, N, 1);          // h -> bufC

  // ---- Layer 2: GATv2(128 -> 128, 1 head) + skip ----
  gemm_k128<128, false><<<ggrid, 256, 0, stream>>>(bufC, Wl2, bl2, bufA, N);   // xl2
  gemm_k128<128, false><<<ggrid, 256, 0, stream>>>(bufC, Wr2, br2, bufB, N);   // xr2
  gemm_k128<128, false><<<ggrid, 256, 0, stream>>>(bufC, skip2_w, skip2_b, bufC, N); // skip2 in-place
  gat_agg<1><<<agrid, 256, 0, stream>>>(bufA, bufB, bufC, att2, b2,
                                        rowptr, csr_src, bufC, N, 0);          // out2 -> bufC

  // ---- MLP head ----
  gemm_k128<128, true><<<ggrid, 256, 0, stream>>>(bufC, mlp1_w, mlp1_b, bufA, N);
  gemm_k128<64, false><<<ggrid, 256, 0, stream>>>(bufA, mlp2_w, mlp2_b, out, N);
}

// Round 6
// 778.180 us; speedup vs baseline: 1.1495x; 1.1495x over previous
//
#include <hip/hip_runtime.h>

#define LEAK 0.2f

typedef __attribute__((ext_vector_type(8))) short short8v;
typedef __attribute__((ext_vector_type(4))) float float4v;

__device__ __forceinline__ ushort f2bf(float f) {
  union { float f; unsigned u; } v; v.f = f;
  unsigned r = v.u + 0x7fffu + ((v.u >> 16) & 1u);  // RNE
  return (ushort)(r >> 16);
}
__device__ __forceinline__ float bf2f(ushort h) {
  union { unsigned u; float f; } v; v.u = ((unsigned)h) << 16;
  return v.f;
}

// ---------------- CSR build (incoming edges per dst) ----------------
__global__ void count_kernel(const int* __restrict__ dstp, int* __restrict__ cnt, int E) {
  int e = blockIdx.x * blockDim.x + threadIdx.x;
  if (e < E) atomicAdd(&cnt[dstp[e]], 1);
}

__global__ __launch_bounds__(1024)
void scan_blocks(const int* __restrict__ cnt, int* __restrict__ tscan,
                 int* __restrict__ bsum, int n) {
  __shared__ int sh[1024];
  int t = threadIdx.x;
  int i = blockIdx.x * 1024 + t;
  sh[t] = (i < n) ? cnt[i] : 0;
  __syncthreads();
  for (int off = 1; off < 1024; off <<= 1) {
    int u = (t >= off) ? sh[t - off] : 0;
    __syncthreads();
    sh[t] += u;
    __syncthreads();
  }
  if (i < n) tscan[i] = sh[t];
  if (t == 1023) bsum[blockIdx.x] = sh[1023];
}

__global__ __launch_bounds__(1024)
void scan_bsums(int* __restrict__ bsum, int* __restrict__ rowptr, int nb, int n) {
  __shared__ int sh[1024];
  int t = threadIdx.x;
  sh[t] = (t < nb) ? bsum[t] : 0;
  __syncthreads();
  for (int off = 1; off < 1024; off <<= 1) {
    int u = (t >= off) ? sh[t - off] : 0;
    __syncthreads();
    sh[t] += u;
    __syncthreads();
  }
  if (t < nb) bsum[t] = sh[t];  // inclusive in place
  if (t == nb - 1) rowptr[n] = sh[t];
}

__global__ __launch_bounds__(1024)
void scan_final(const int* __restrict__ cnt, const int* __restrict__ tscan,
                const int* __restrict__ bsum, int* __restrict__ rowptr, int n) {
  int i = blockIdx.x * 1024 + threadIdx.x;
  if (i < n) {
    int bpref = (blockIdx.x == 0) ? 0 : bsum[blockIdx.x - 1];
    rowptr[i] = bpref + tscan[i] - cnt[i];
  }
}

__global__ void fill_kernel(const int* __restrict__ srcp, const int* __restrict__ dstp,
                            const int* __restrict__ rowptr, int* __restrict__ cur,
                            int* __restrict__ csr_src, int E) {
  int e = blockIdx.x * blockDim.x + threadIdx.x;
  if (e < E) {
    int d = dstp[e];
    int pos = atomicAdd(&cur[d], 1);
    csr_src[rowptr[d] + pos] = srcp[e];
  }
}

// ---------------- bf16 split helpers ----------------
// x fp32 [n] -> hi,lo bf16 (a ~= hi + lo, rel err ~2^-17)
__global__ void split_f32(const float* __restrict__ a, ushort* __restrict__ hi,
                          ushort* __restrict__ lo, int n) {
  int i = (blockIdx.x * blockDim.x + threadIdx.x) * 4;
  if (i >= n) return;
  float4 v = *(const float4*)(a + i);
  ushort h[4], l[4];
  float vv[4] = {v.x, v.y, v.z, v.w};
#pragma unroll
  for (int j = 0; j < 4; ++j) {
    h[j] = f2bf(vv[j]);
    l[j] = f2bf(vv[j] - bf2f(h[j]));
  }
  *(ushort4*)(hi + i) = make_ushort4(h[0], h[1], h[2], h[3]);
  *(ushort4*)(lo + i) = make_ushort4(l[0], l[1], l[2], l[3]);
}

// Pack W fp32 [128][NOUT] into per-lane MFMA B-fragments (bf16 hi|lo parts).
// Frag (nt, ks, lane): 8 elems j: W[ks*32 + (lane>>4)*8 + j][nt*16 + (lane&15)].
// hi part at pk[0..], lo part at pk + NT*4*64*8.
__global__ void pack_w(const float* __restrict__ W, ushort* __restrict__ pk, int NOUT) {
  int t = blockIdx.x * blockDim.x + threadIdx.x;
  int NT = NOUT / 16;
  int total = NT * 4 * 64;
  if (t >= total) return;
  int lane = t & 63;
  int ks = (t >> 6) & 3;
  int nt = t >> 8;
  int col = nt * 16 + (lane & 15);
  int k0 = ks * 32 + (lane >> 4) * 8;
  ushort h[8], l[8];
#pragma unroll
  for (int j = 0; j < 8; ++j) {
    float v = W[(size_t)(k0 + j) * NOUT + col];
    h[j] = f2bf(v);
    l[j] = f2bf(v - bf2f(h[j]));
  }
  size_t fb = ((size_t)(nt * 4 + ks) * 64 + lane) * 8;
  size_t fragsz = (size_t)total * 8;
#pragma unroll
  for (int j = 0; j < 8; ++j) { pk[fb + j] = h[j]; pk[fragsz + fb + j] = l[j]; }
}

// ---------- MFMA GEMM: C[M,NOUT] = (Ahi+Alo)[M,128] @ W[128,NOUT] + bias ----------
// bf16x3 split-product: acc += ah*bh + ah*bl + al*bh (err ~2^-17 rel, fp32 accum).
// Block: 256 thr = 4 waves, tile 64 rows x NOUT cols. No LDS; A tile (16KB hi+lo)
// and packed W (<=64KB) are L1-resident. MODE 0: fp32 out; 1: relu + split out.
template<int NOUT, int MODE>
__global__ __launch_bounds__(256)
void gemm_mfma(const ushort* __restrict__ Ahi, const ushort* __restrict__ Alo,
               const ushort* __restrict__ Wpk, const float* __restrict__ bias,
               float* __restrict__ Cf, ushort* __restrict__ Chi, ushort* __restrict__ Clo,
               int M) {
  constexpr int NT = NOUT / 16;   // n-tiles total: 8 or 4
  constexpr int WNT = NT / 4;     // n-tiles per wave: 2 or 1
  int tid = threadIdx.x;
  int wid = tid >> 6, lane = tid & 63;
  int l15 = lane & 15, lh = lane >> 4;
  int row0 = blockIdx.x * 64;

  int arow[4];
#pragma unroll
  for (int mt = 0; mt < 4; ++mt) { int rr = row0 + mt * 16 + l15; arow[mt] = rr < M ? rr : M - 1; }

  float4v acc[4][WNT];
#pragma unroll
  for (int mt = 0; mt < 4; ++mt)
#pragma unroll
    for (int nt2 = 0; nt2 < WNT; ++nt2) {
      acc[mt][nt2][0] = 0.f; acc[mt][nt2][1] = 0.f; acc[mt][nt2][2] = 0.f; acc[mt][nt2][3] = 0.f;
    }

  const size_t fragsz = (size_t)NT * 4 * 64 * 8;
#pragma unroll
  for (int ks = 0; ks < 4; ++ks) {
    short8v bh[WNT], bl[WNT];
#pragma unroll
    for (int nt2 = 0; nt2 < WNT; ++nt2) {
      int nt = wid * WNT + nt2;
      size_t fb = ((size_t)(nt * 4 + ks) * 64 + lane) * 8;
      bh[nt2] = *(const short8v*)(Wpk + fb);
      bl[nt2] = *(const short8v*)(Wpk + fragsz + fb);
    }
#pragma unroll
    for (int mt = 0; mt < 4; ++mt) {
      size_t ao = (size_t)arow[mt] * 128 + ks * 32 + lh * 8;
      short8v ah = *(const short8v*)(Ahi + ao);
      short8v al = *(const short8v*)(Alo + ao);
#pragma unroll
      for (int nt2 = 0; nt2 < WNT; ++nt2) {
        acc[mt][nt2] = __builtin_amdgcn_mfma_f32_16x16x32_bf16(ah, bh[nt2], acc[mt][nt2], 0, 0, 0);
        acc[mt][nt2] = __builtin_amdgcn_mfma_f32_16x16x32_bf16(ah, bl[nt2], acc[mt][nt2], 0, 0, 0);
        acc[mt][nt2] = __builtin_amdgcn_mfma_f32_16x16x32_bf16(al, bh[nt2], acc[mt][nt2], 0, 0, 0);
      }
    }
  }

  // D layout per tile: col = lane&15, row = (lane>>4)*4 + reg
#pragma unroll
  for (int mt = 0; mt < 4; ++mt) {
#pragma unroll
    for (int nt2 = 0; nt2 < WNT; ++nt2) {
      int col = (wid * WNT + nt2) * 16 + l15;
      float bb = bias[col];
#pragma unroll
      for (int r = 0; r < 4; ++r) {
        int rr = row0 + mt * 16 + lh * 4 + r;
        if (rr < M) {
          float v = acc[mt][nt2][r] + bb;
          if (MODE == 1) {
            v = fmaxf(v, 0.f);
            ushort h = f2bf(v);
            Chi[(size_t)rr * NOUT + col] = h;
            Clo[(size_t)rr * NOUT + col] = f2bf(v - bf2f(h));
          } else {
            Cf[(size_t)rr * NOUT + col] = v;
          }
        }
      }
    }
  }
}

// ---------- GATv2 aggregation: one wave per node, 4 edges in flight ----------
// SPLIT: write bf16 hi/lo (output feeds only GEMMs); else fp32.
template<int H, bool SPLIT>
__global__ __launch_bounds__(256)
void gat_agg(const float* __restrict__ xl, const float* __restrict__ xr,
             const float* __restrict__ skip, const float* __restrict__ att,
             const float* __restrict__ gbias, const int* __restrict__ rowptr,
             const int* __restrict__ csr_src, float* __restrict__ out,
             ushort* __restrict__ outhi, ushort* __restrict__ outlo,
             int n, int relu) {
  constexpr int C = 128 / H;
  constexpr int G = C / 2;
  int wid = blockIdx.x * (blockDim.x >> 6) + (threadIdx.x >> 6);
  if (wid >= n) return;
  int lane = threadIdx.x & 63;
  size_t base = (size_t)wid * 128 + lane * 2;
  float2 xrv = *(const float2*)(xr + base);
  float2 av = *(const float2*)(att + lane * 2);
  float2 acc = make_float2(0.f, 0.f);
  float denom = 0.f;
  int e0 = rowptr[wid], e1 = rowptr[wid + 1];

  // self-loop
  {
    float2 xlv = *(const float2*)(xl + base);
    float ex = xlv.x + xrv.x; ex = ex > 0.f ? ex : LEAK * ex;
    float ey = xlv.y + xrv.y; ey = ey > 0.f ? ey : LEAK * ey;
    float p = ex * av.x + ey * av.y;
#pragma unroll
    for (int o = 1; o < G; o <<= 1) p += __shfl_xor(p, o, 64);
    float w = __expf(p);
    denom += w;
    acc.x += w * xlv.x;
    acc.y += w * xlv.y;
  }

  int idx = e0;
  for (; idx + 4 <= e1; idx += 4) {
    int s0 = csr_src[idx], s1 = csr_src[idx + 1], s2 = csr_src[idx + 2], s3 = csr_src[idx + 3];
    float2 v0 = *(const float2*)(xl + (size_t)s0 * 128 + lane * 2);
    float2 v1 = *(const float2*)(xl + (size_t)s1 * 128 + lane * 2);
    float2 v2 = *(const float2*)(xl + (size_t)s2 * 128 + lane * 2);
    float2 v3 = *(const float2*)(xl + (size_t)s3 * 128 + lane * 2);
    float ex, ey;
    ex = v0.x + xrv.x; ex = ex > 0.f ? ex : LEAK * ex;
    ey = v0.y + xrv.y; ey = ey > 0.f ? ey : LEAK * ey;
    float p0 = ex * av.x + ey * av.y;
    ex = v1.x + xrv.x; ex = ex > 0.f ? ex : LEAK * ex;
    ey = v1.y + xrv.y; ey = ey > 0.f ? ey : LEAK * ey;
    float p1 = ex * av.x + ey * av.y;
    ex = v2.x + xrv.x; ex = ex > 0.f ? ex : LEAK * ex;
    ey = v2.y + xrv.y; ey = ey > 0.f ? ey : LEAK * ey;
    float p2 = ex * av.x + ey * av.y;
    ex = v3.x + xrv.x; ex = ex > 0.f ? ex : LEAK * ex;
    ey = v3.y + xrv.y; ey = ey > 0.f ? ey : LEAK * ey;
    float p3 = ex * av.x + ey * av.y;
#pragma unroll
    for (int o = 1; o < G; o <<= 1) {
      p0 += __shfl_xor(p0, o, 64);
      p1 += __shfl_xor(p1, o, 64);
      p2 += __shfl_xor(p2, o, 64);
      p3 += __shfl_xor(p3, o, 64);
    }
    float w0 = __expf(p0), w1 = __expf(p1), w2 = __expf(p2), w3 = __expf(p3);
    denom += (w0 + w1) + (w2 + w3);
    acc.x += w0 * v0.x + w1 * v1.x + w2 * v2.x + w3 * v3.x;
    acc.y += w0 * v0.y + w1 * v1.y + w2 * v2.y + w3 * v3.y;
  }
  for (; idx < e1; ++idx) {
    int src = csr_src[idx];
    float2 xlv = *(const float2*)(xl + (size_t)src * 128 + lane * 2);
    float ex = xlv.x + xrv.x; ex = ex > 0.f ? ex : LEAK * ex;
    float ey = xlv.y + xrv.y; ey = ey > 0.f ? ey : LEAK * ey;
    float p = ex * av.x + ey * av.y;
#pragma unroll
    for (int o = 1; o < G; o <<= 1) p += __shfl_xor(p, o, 64);
    float w = __expf(p);
    denom += w;
    acc.x += w * xlv.x;
    acc.y += w * xlv.y;
  }

  float inv = 1.f / denom;
  float2 sk = *(const float2*)(skip + base);
  float2 gb = *(const float2*)(gbias + lane * 2);
  float ox = acc.x * inv + gb.x + sk.x;
  float oy = acc.y * inv + gb.y + sk.y;
  if (relu) { ox = fmaxf(ox, 0.f); oy = fmaxf(oy, 0.f); }
  if (SPLIT) {
    ushort hx = f2bf(ox), hy = f2bf(oy);
    ushort lx = f2bf(ox - bf2f(hx)), ly = f2bf(oy - bf2f(hy));
    *(ushort2*)(outhi + base) = make_ushort2(hx, hy);
    *(ushort2*)(outlo + base) = make_ushort2(lx, ly);
  } else {
    *(float2*)(out + base) = make_float2(ox, oy);
  }
}

extern "C" void kernel_launch(void* const* d_in, const int* in_sizes, int n_in,
                              void* d_out, int out_size, void* d_ws, size_t ws_size,
                              hipStream_t stream) {
  const float* x       = (const float*)d_in[0];
  const int* ei        = (const int*)d_in[1];
  const float* Wl1     = (const float*)d_in[2];
  const float* bl1     = (const float*)d_in[3];
  const float* Wr1     = (const float*)d_in[4];
  const float* br1     = (const float*)d_in[5];
  const float* att1    = (const float*)d_in[6];
  const float* b1      = (const float*)d_in[7];
  const float* Wl2     = (const float*)d_in[8];
  const float* bl2     = (const float*)d_in[9];
  const float* Wr2     = (const float*)d_in[10];
  const float* br2     = (const float*)d_in[11];
  const float* att2    = (const float*)d_in[12];
  const float* b2      = (const float*)d_in[13];
  const float* skip1_w = (const float*)d_in[14];
  const float* skip1_b = (const float*)d_in[15];
  const float* skip2_w = (const float*)d_in[16];
  const float* skip2_b = (const float*)d_in[17];
  const float* mlp1_w  = (const float*)d_in[18];
  const float* mlp1_b  = (const float*)d_in[19];
  const float* mlp2_w  = (const float*)d_in[20];
  const float* mlp2_b  = (const float*)d_in[21];

  const int N = in_sizes[0] / 128;
  const int E = in_sizes[1] / 2;
  float* out = (float*)d_out;

  char* ws = (char*)d_ws;
  size_t off = 0;
  auto alloc = [&](size_t bytes) -> void* {
    void* p = ws + off;
    off = (off + bytes + 255) & ~(size_t)255;
    return p;
  };
  int* rowptr  = (int*)alloc((size_t)(N + 1) * sizeof(int));
  int* cnt     = (int*)alloc((size_t)N * sizeof(int));
  int* tscan   = (int*)alloc((size_t)N * sizeof(int));
  int* bsum    = (int*)alloc((size_t)1024 * sizeof(int));
  int* csr_src = (int*)alloc((size_t)E * sizeof(int));
  ushort* wpk[8];
  for (int i = 0; i < 8; ++i) wpk[i] = (ushort*)alloc(128 * 128 * 2 * sizeof(ushort));
  ushort* p0hi = (ushort*)alloc((size_t)N * 128 * sizeof(ushort));
  ushort* p0lo = (ushort*)alloc((size_t)N * 128 * sizeof(ushort));
  float* bufA  = (float*)alloc((size_t)N * 128 * sizeof(float));
  float* bufB  = (float*)alloc((size_t)N * 128 * sizeof(float));
  float* bufC  = (float*)alloc((size_t)N * 128 * sizeof(float));
  // mlp1 split output carved from (dead-by-then) bufA
  ushort* m1hi = (ushort*)bufA;
  ushort* m1lo = m1hi + (size_t)N * 128;

  const int* srcp = ei;
  const int* dstp = ei + E;

  const int egrid = (E + 255) / 256;
  const int ggrid = (N + 63) / 64;
  const int agrid = (N + 3) / 4;
  const int nb = (N + 1023) / 1024;

  // CSR by dst (shared by both GAT layers)
  hipMemsetAsync(cnt, 0, (size_t)N * sizeof(int), stream);
  count_kernel<<<egrid, 256, 0, stream>>>(dstp, cnt, E);
  scan_blocks<<<nb, 1024, 0, stream>>>(cnt, tscan, bsum, N);
  scan_bsums<<<1, 1024, 0, stream>>>(bsum, rowptr, nb, N);
  scan_final<<<nb, 1024, 0, stream>>>(cnt, tscan, bsum, rowptr, N);
  hipMemsetAsync(cnt, 0, (size_t)N * sizeof(int), stream);
  fill_kernel<<<egrid, 256, 0, stream>>>(srcp, dstp, rowptr, cnt, csr_src, E);

  // Weight packs + x split
  pack_w<<<8, 256, 0, stream>>>(Wl1, wpk[0], 128);
  pack_w<<<8, 256, 0, stream>>>(Wr1, wpk[1], 128);
  pack_w<<<8, 256, 0, stream>>>(skip1_w, wpk[2], 128);
  pack_w<<<8, 256, 0, stream>>>(Wl2, wpk[3], 128);
  pack_w<<<8, 256, 0, stream>>>(Wr2, wpk[4], 128);
  pack_w<<<8, 256, 0, stream>>>(skip2_w, wpk[5], 128);
  pack_w<<<8, 256, 0, stream>>>(mlp1_w, wpk[6], 128);
  pack_w<<<4, 256, 0, stream>>>(mlp2_w, wpk[7], 64);
  split_f32<<<(N * 128 / 4 + 255) / 256, 256, 0, stream>>>(x, p0hi, p0lo, N * 128);

  // ---- Layer 1: GATv2(128 -> 4x32 concat) + skip + ReLU ----
  gemm_mfma<128, 0><<<ggrid, 256, 0, stream>>>(p0hi, p0lo, wpk[0], bl1, bufA, nullptr, nullptr, N);
  gemm_mfma<128, 0><<<ggrid, 256, 0, stream>>>(p0hi, p0lo, wpk[1], br1, bufB, nullptr, nullptr, N);
  gemm_mfma<128, 0><<<ggrid, 256, 0, stream>>>(p0hi, p0lo, wpk[2], skip1_b, bufC, nullptr, nullptr, N);
  gat_agg<4, true><<<agrid, 256, 0, stream>>>(bufA, bufB, bufC, att1, b1,
                                              rowptr, csr_src, nullptr, p0hi, p0lo, N, 1);

  // ---- Layer 2: GATv2(128 -> 128, 1 head) + skip ----
  gemm_mfma<128, 0><<<ggrid, 256, 0, stream>>>(p0hi, p0lo, wpk[3], bl2, bufA, nullptr, nullptr, N);
  gemm_mfma<128, 0><<<ggrid, 256, 0, stream>>>(p0hi, p0lo, wpk[4], br2, bufB, nullptr, nullptr, N);
  gemm_mfma<128, 0><<<ggrid, 256, 0, stream>>>(p0hi, p0lo, wpk[5], skip2_b, bufC, nullptr, nullptr, N);
  gat_agg<1, true><<<agrid, 256, 0, stream>>>(bufA, bufB, bufC, att2, b2,
                                              rowptr, csr_src, nullptr, p0hi, p0lo, N, 0);

  // ---- MLP head ----
  gemm_mfma<128, 1><<<ggrid, 256, 0, stream>>>(p0hi, p0lo, wpk[6], mlp1_b, nullptr, m1hi, m1lo, N);
  gemm_mfma<64, 0><<<ggrid, 256, 0, stream>>>(m1hi, m1lo, wpk[7], mlp2_b, out, nullptr, nullptr, N);
}

// Round 7
// 709.099 us; speedup vs baseline: 1.2614x; 1.0974x over previous
//
#include <hip/hip_runtime.h>

#define LEAK 0.2f

typedef __attribute__((ext_vector_type(8))) short short8v;
typedef __attribute__((ext_vector_type(4))) float float4v;

__device__ __forceinline__ ushort f2bf(float f) {
  union { float f; unsigned u; } v; v.f = f;
  unsigned r = v.u + 0x7fffu + ((v.u >> 16) & 1u);  // RNE
  return (ushort)(r >> 16);
}
__device__ __forceinline__ float bf2f(ushort h) {
  union { unsigned u; float f; } v; v.u = ((unsigned)h) << 16;
  return v.f;
}

// ---------------- CSR build (incoming edges per dst) ----------------
__global__ void count_kernel(const int* __restrict__ dstp, int* __restrict__ cnt, int E) {
  int e = blockIdx.x * blockDim.x + threadIdx.x;
  if (e < E) atomicAdd(&cnt[dstp[e]], 1);
}

__global__ __launch_bounds__(1024)
void scan_blocks(const int* __restrict__ cnt, int* __restrict__ tscan,
                 int* __restrict__ bsum, int n) {
  __shared__ int sh[1024];
  int t = threadIdx.x;
  int i = blockIdx.x * 1024 + t;
  sh[t] = (i < n) ? cnt[i] : 0;
  __syncthreads();
  for (int off = 1; off < 1024; off <<= 1) {
    int u = (t >= off) ? sh[t - off] : 0;
    __syncthreads();
    sh[t] += u;
    __syncthreads();
  }
  if (i < n) tscan[i] = sh[t];
  if (t == 1023) bsum[blockIdx.x] = sh[1023];
}

__global__ __launch_bounds__(1024)
void scan_bsums(int* __restrict__ bsum, int* __restrict__ rowptr, int nb, int n) {
  __shared__ int sh[1024];
  int t = threadIdx.x;
  sh[t] = (t < nb) ? bsum[t] : 0;
  __syncthreads();
  for (int off = 1; off < 1024; off <<= 1) {
    int u = (t >= off) ? sh[t - off] : 0;
    __syncthreads();
    sh[t] += u;
    __syncthreads();
  }
  if (t < nb) bsum[t] = sh[t];  // inclusive in place
  if (t == nb - 1) rowptr[n] = sh[t];
}

__global__ __launch_bounds__(1024)
void scan_final(const int* __restrict__ cnt, const int* __restrict__ tscan,
                const int* __restrict__ bsum, int* __restrict__ rowptr, int n) {
  int i = blockIdx.x * 1024 + threadIdx.x;
  if (i < n) {
    int bpref = (blockIdx.x == 0) ? 0 : bsum[blockIdx.x - 1];
    rowptr[i] = bpref + tscan[i] - cnt[i];
  }
}

__global__ void fill_kernel(const int* __restrict__ srcp, const int* __restrict__ dstp,
                            const int* __restrict__ rowptr, int* __restrict__ cur,
                            int* __restrict__ csr_src, int E) {
  int e = blockIdx.x * blockDim.x + threadIdx.x;
  if (e < E) {
    int d = dstp[e];
    int pos = atomicAdd(&cur[d], 1);
    csr_src[rowptr[d] + pos] = srcp[e];
  }
}

// ---------------- bf16 split helpers ----------------
__global__ void split_f32(const float* __restrict__ a, ushort* __restrict__ hi,
                          ushort* __restrict__ lo, int n) {
  int i = (blockIdx.x * blockDim.x + threadIdx.x) * 4;
  if (i >= n) return;
  float4 v = *(const float4*)(a + i);
  ushort h[4], l[4];
  float vv[4] = {v.x, v.y, v.z, v.w};
#pragma unroll
  for (int j = 0; j < 4; ++j) {
    h[j] = f2bf(vv[j]);
    l[j] = f2bf(vv[j] - bf2f(h[j]));
  }
  *(ushort4*)(hi + i) = make_ushort4(h[0], h[1], h[2], h[3]);
  *(ushort4*)(lo + i) = make_ushort4(l[0], l[1], l[2], l[3]);
}

// Pack all 8 weight matrices in ONE launch. Frag (nt, ks, lane), 8 elems j:
// W[ks*32 + (lane>>4)*8 + j][nt*16 + (lane&15)]. hi at [0..), lo at +total*8.
struct PackArgs {
  const float* w[8];
  ushort* o[8];
  int nout[8];
};
__global__ __launch_bounds__(256)
void pack_all(PackArgs pa) {
  int wsel = blockIdx.x >> 3;   // 8 sub-blocks per matrix
  int sub = blockIdx.x & 7;
  const float* W = pa.w[wsel];
  ushort* pk = pa.o[wsel];
  int NOUT = pa.nout[wsel];
  int NT = NOUT / 16;
  int total = NT * 4 * 64;
  int t = sub * 256 + threadIdx.x;
  if (t >= total) return;
  int lane = t & 63;
  int ks = (t >> 6) & 3;
  int nt = t >> 8;
  int col = nt * 16 + (lane & 15);
  int k0 = ks * 32 + (lane >> 4) * 8;
  ushort h[8], l[8];
#pragma unroll
  for (int j = 0; j < 8; ++j) {
    float v = W[(size_t)(k0 + j) * NOUT + col];
    h[j] = f2bf(v);
    l[j] = f2bf(v - bf2f(h[j]));
  }
  size_t fb = ((size_t)(nt * 4 + ks) * 64 + lane) * 8;
  size_t fragsz = (size_t)total * 8;
#pragma unroll
  for (int j = 0; j < 8; ++j) { pk[fb + j] = h[j]; pk[fragsz + fb + j] = l[j]; }
}

// ---------- Fused triple MFMA GEMM: Cp = (Ahi+Alo) @ Wp + bp, p=0,1,2 ----------
// 512 thr = 8 waves; wave w owns col-tile [w*16, w*16+16) of ALL THREE outputs.
// A tile (64 rows, 16KB hi + 16KB lo) read once per block, L1-resident, shared
// by the 3 products. bf16x3: acc += ah*bh + ah*bl + al*bh. 144 MFMA/thread.
__global__ __launch_bounds__(512)
void gemm3_mfma(const ushort* __restrict__ Ahi, const ushort* __restrict__ Alo,
                const ushort* __restrict__ W0, const ushort* __restrict__ W1,
                const ushort* __restrict__ W2,
                const float* __restrict__ b0, const float* __restrict__ b1,
                const float* __restrict__ b2,
                float* __restrict__ C0, float* __restrict__ C1, float* __restrict__ C2,
                int M) {
  int tid = threadIdx.x;
  int w = tid >> 6, lane = tid & 63;
  int l15 = lane & 15, lh = lane >> 4;
  int row0 = blockIdx.x * 64;

  const ushort* Wp[3] = {W0, W1, W2};
  const float* bp[3] = {b0, b1, b2};
  float* Cp[3] = {C0, C1, C2};

  int arow[4];
#pragma unroll
  for (int mt = 0; mt < 4; ++mt) { int rr = row0 + mt * 16 + l15; arow[mt] = rr < M ? rr : M - 1; }

  float4v acc[3][4];
#pragma unroll
  for (int p = 0; p < 3; ++p)
#pragma unroll
    for (int mt = 0; mt < 4; ++mt) {
      acc[p][mt][0] = 0.f; acc[p][mt][1] = 0.f; acc[p][mt][2] = 0.f; acc[p][mt][3] = 0.f;
    }

  const size_t fragsz = (size_t)8 * 4 * 64 * 8;  // NT=8
#pragma unroll
  for (int ks = 0; ks < 4; ++ks) {
    short8v bh[3], bl[3];
    size_t fb = ((size_t)(w * 4 + ks) * 64 + lane) * 8;
#pragma unroll
    for (int p = 0; p < 3; ++p) {
      bh[p] = *(const short8v*)(Wp[p] + fb);
      bl[p] = *(const short8v*)(Wp[p] + fragsz + fb);
    }
#pragma unroll
    for (int mt = 0; mt < 4; ++mt) {
      size_t ao = (size_t)arow[mt] * 128 + ks * 32 + lh * 8;
      short8v ah = *(const short8v*)(Ahi + ao);
      short8v al = *(const short8v*)(Alo + ao);
#pragma unroll
      for (int p = 0; p < 3; ++p) {
        acc[p][mt] = __builtin_amdgcn_mfma_f32_16x16x32_bf16(ah, bh[p], acc[p][mt], 0, 0, 0);
        acc[p][mt] = __builtin_amdgcn_mfma_f32_16x16x32_bf16(ah, bl[p], acc[p][mt], 0, 0, 0);
        acc[p][mt] = __builtin_amdgcn_mfma_f32_16x16x32_bf16(al, bh[p], acc[p][mt], 0, 0, 0);
      }
    }
  }

  int col = w * 16 + l15;
#pragma unroll
  for (int p = 0; p < 3; ++p) {
    float bb = bp[p][col];
#pragma unroll
    for (int mt = 0; mt < 4; ++mt) {
#pragma unroll
      for (int r = 0; r < 4; ++r) {
        int rr = row0 + mt * 16 + lh * 4 + r;
        if (rr < M) Cp[p][(size_t)rr * 128 + col] = acc[p][mt][r] + bb;
      }
    }
  }
}

// ---------- single MFMA GEMM (MLP head) ----------
template<int NOUT, int MODE>
__global__ __launch_bounds__(256)
void gemm_mfma(const ushort* __restrict__ Ahi, const ushort* __restrict__ Alo,
               const ushort* __restrict__ Wpk, const float* __restrict__ bias,
               float* __restrict__ Cf, ushort* __restrict__ Chi, ushort* __restrict__ Clo,
               int M) {
  constexpr int NT = NOUT / 16;
  constexpr int WNT = NT / 4;
  int tid = threadIdx.x;
  int wid = tid >> 6, lane = tid & 63;
  int l15 = lane & 15, lh = lane >> 4;
  int row0 = blockIdx.x * 64;

  int arow[4];
#pragma unroll
  for (int mt = 0; mt < 4; ++mt) { int rr = row0 + mt * 16 + l15; arow[mt] = rr < M ? rr : M - 1; }

  float4v acc[4][WNT];
#pragma unroll
  for (int mt = 0; mt < 4; ++mt)
#pragma unroll
    for (int nt2 = 0; nt2 < WNT; ++nt2) {
      acc[mt][nt2][0] = 0.f; acc[mt][nt2][1] = 0.f; acc[mt][nt2][2] = 0.f; acc[mt][nt2][3] = 0.f;
    }

  const size_t fragsz = (size_t)NT * 4 * 64 * 8;
#pragma unroll
  for (int ks = 0; ks < 4; ++ks) {
    short8v bh[WNT], bl[WNT];
#pragma unroll
    for (int nt2 = 0; nt2 < WNT; ++nt2) {
      int nt = wid * WNT + nt2;
      size_t fb = ((size_t)(nt * 4 + ks) * 64 + lane) * 8;
      bh[nt2] = *(const short8v*)(Wpk + fb);
      bl[nt2] = *(const short8v*)(Wpk + fragsz + fb);
    }
#pragma unroll
    for (int mt = 0; mt < 4; ++mt) {
      size_t ao = (size_t)arow[mt] * 128 + ks * 32 + lh * 8;
      short8v ah = *(const short8v*)(Ahi + ao);
      short8v al = *(const short8v*)(Alo + ao);
#pragma unroll
      for (int nt2 = 0; nt2 < WNT; ++nt2) {
        acc[mt][nt2] = __builtin_amdgcn_mfma_f32_16x16x32_bf16(ah, bh[nt2], acc[mt][nt2], 0, 0, 0);
        acc[mt][nt2] = __builtin_amdgcn_mfma_f32_16x16x32_bf16(ah, bl[nt2], acc[mt][nt2], 0, 0, 0);
        acc[mt][nt2] = __builtin_amdgcn_mfma_f32_16x16x32_bf16(al, bh[nt2], acc[mt][nt2], 0, 0, 0);
      }
    }
  }

#pragma unroll
  for (int mt = 0; mt < 4; ++mt) {
#pragma unroll
    for (int nt2 = 0; nt2 < WNT; ++nt2) {
      int col = (wid * WNT + nt2) * 16 + l15;
      float bb = bias[col];
#pragma unroll
      for (int r = 0; r < 4; ++r) {
        int rr = row0 + mt * 16 + lh * 4 + r;
        if (rr < M) {
          float v = acc[mt][nt2][r] + bb;
          if (MODE == 1) {
            v = fmaxf(v, 0.f);
            ushort h = f2bf(v);
            Chi[(size_t)rr * NOUT + col] = h;
            Clo[(size_t)rr * NOUT + col] = f2bf(v - bf2f(h));
          } else {
            Cf[(size_t)rr * NOUT + col] = v;
          }
        }
      }
    }
  }
}

// ---------- GATv2 aggregation: one wave per node, 4 edges in flight ----------
template<int H, bool SPLIT>
__global__ __launch_bounds__(256)
void gat_agg(const float* __restrict__ xl, const float* __restrict__ xr,
             const float* __restrict__ skip, const float* __restrict__ att,
             const float* __restrict__ gbias, const int* __restrict__ rowptr,
             const int* __restrict__ csr_src, float* __restrict__ out,
             ushort* __restrict__ outhi, ushort* __restrict__ outlo,
             int n, int relu) {
  constexpr int C = 128 / H;
  constexpr int G = C / 2;
  int wid = blockIdx.x * (blockDim.x >> 6) + (threadIdx.x >> 6);
  if (wid >= n) return;
  int lane = threadIdx.x & 63;
  size_t base = (size_t)wid * 128 + lane * 2;
  float2 xrv = *(const float2*)(xr + base);
  float2 av = *(const float2*)(att + lane * 2);
  float2 acc = make_float2(0.f, 0.f);
  float denom = 0.f;
  int e0 = rowptr[wid], e1 = rowptr[wid + 1];

  // self-loop
  {
    float2 xlv = *(const float2*)(xl + base);
    float ex = xlv.x + xrv.x; ex = ex > 0.f ? ex : LEAK * ex;
    float ey = xlv.y + xrv.y; ey = ey > 0.f ? ey : LEAK * ey;
    float p = ex * av.x + ey * av.y;
#pragma unroll
    for (int o = 1; o < G; o <<= 1) p += __shfl_xor(p, o, 64);
    float w = __expf(p);
    denom += w;
    acc.x += w * xlv.x;
    acc.y += w * xlv.y;
  }

  int idx = e0;
  for (; idx + 4 <= e1; idx += 4) {
    int s0 = csr_src[idx], s1 = csr_src[idx + 1], s2 = csr_src[idx + 2], s3 = csr_src[idx + 3];
    float2 v0 = *(const float2*)(xl + (size_t)s0 * 128 + lane * 2);
    float2 v1 = *(const float2*)(xl + (size_t)s1 * 128 + lane * 2);
    float2 v2 = *(const float2*)(xl + (size_t)s2 * 128 + lane * 2);
    float2 v3 = *(const float2*)(xl + (size_t)s3 * 128 + lane * 2);
    float ex, ey;
    ex = v0.x + xrv.x; ex = ex > 0.f ? ex : LEAK * ex;
    ey = v0.y + xrv.y; ey = ey > 0.f ? ey : LEAK * ey;
    float p0 = ex * av.x + ey * av.y;
    ex = v1.x + xrv.x; ex = ex > 0.f ? ex : LEAK * ex;
    ey = v1.y + xrv.y; ey = ey > 0.f ? ey : LEAK * ey;
    float p1 = ex * av.x + ey * av.y;
    ex = v2.x + xrv.x; ex = ex > 0.f ? ex : LEAK * ex;
    ey = v2.y + xrv.y; ey = ey > 0.f ? ey : LEAK * ey;
    float p2 = ex * av.x + ey * av.y;
    ex = v3.x + xrv.x; ex = ex > 0.f ? ex : LEAK * ex;
    ey = v3.y + xrv.y; ey = ey > 0.f ? ey : LEAK * ey;
    float p3 = ex * av.x + ey * av.y;
#pragma unroll
    for (int o = 1; o < G; o <<= 1) {
      p0 += __shfl_xor(p0, o, 64);
      p1 += __shfl_xor(p1, o, 64);
      p2 += __shfl_xor(p2, o, 64);
      p3 += __shfl_xor(p3, o, 64);
    }
    float w0 = __expf(p0), w1 = __expf(p1), w2 = __expf(p2), w3 = __expf(p3);
    denom += (w0 + w1) + (w2 + w3);
    acc.x += w0 * v0.x + w1 * v1.x + w2 * v2.x + w3 * v3.x;
    acc.y += w0 * v0.y + w1 * v1.y + w2 * v2.y + w3 * v3.y;
  }
  for (; idx < e1; ++idx) {
    int src = csr_src[idx];
    float2 xlv = *(const float2*)(xl + (size_t)src * 128 + lane * 2);
    float ex = xlv.x + xrv.x; ex = ex > 0.f ? ex : LEAK * ex;
    float ey = xlv.y + xrv.y; ey = ey > 0.f ? ey : LEAK * ey;
    float p = ex * av.x + ey * av.y;
#pragma unroll
    for (int o = 1; o < G; o <<= 1) p += __shfl_xor(p, o, 64);
    float w = __expf(p);
    denom += w;
    acc.x += w * xlv.x;
    acc.y += w * xlv.y;
  }

  float inv = 1.f / denom;
  float2 sk = *(const float2*)(skip + base);
  float2 gb = *(const float2*)(gbias + lane * 2);
  float ox = acc.x * inv + gb.x + sk.x;
  float oy = acc.y * inv + gb.y + sk.y;
  if (relu) { ox = fmaxf(ox, 0.f); oy = fmaxf(oy, 0.f); }
  if (SPLIT) {
    ushort hx = f2bf(ox), hy = f2bf(oy);
    ushort lx = f2bf(ox - bf2f(hx)), ly = f2bf(oy - bf2f(hy));
    *(ushort2*)(outhi + base) = make_ushort2(hx, hy);
    *(ushort2*)(outlo + base) = make_ushort2(lx, ly);
  } else {
    *(float2*)(out + base) = make_float2(ox, oy);
  }
}

extern "C" void kernel_launch(void* const* d_in, const int* in_sizes, int n_in,
                              void* d_out, int out_size, void* d_ws, size_t ws_size,
                              hipStream_t stream) {
  const float* x       = (const float*)d_in[0];
  const int* ei        = (const int*)d_in[1];
  const float* Wl1     = (const float*)d_in[2];
  const float* bl1     = (const float*)d_in[3];
  const float* Wr1     = (const float*)d_in[4];
  const float* br1     = (const float*)d_in[5];
  const float* att1    = (const float*)d_in[6];
  const float* b1      = (const float*)d_in[7];
  const float* Wl2     = (const float*)d_in[8];
  const float* bl2     = (const float*)d_in[9];
  const float* Wr2     = (const float*)d_in[10];
  const float* br2     = (const float*)d_in[11];
  const float* att2    = (const float*)d_in[12];
  const float* b2      = (const float*)d_in[13];
  const float* skip1_w = (const float*)d_in[14];
  const float* skip1_b = (const float*)d_in[15];
  const float* skip2_w = (const float*)d_in[16];
  const float* skip2_b = (const float*)d_in[17];
  const float* mlp1_w  = (const float*)d_in[18];
  const float* mlp1_b  = (const float*)d_in[19];
  const float* mlp2_w  = (const float*)d_in[20];
  const float* mlp2_b  = (const float*)d_in[21];

  const int N = in_sizes[0] / 128;
  const int E = in_sizes[1] / 2;
  float* out = (float*)d_out;

  char* ws = (char*)d_ws;
  size_t off = 0;
  auto alloc = [&](size_t bytes) -> void* {
    void* p = ws + off;
    off = (off + bytes + 255) & ~(size_t)255;
    return p;
  };
  int* rowptr  = (int*)alloc((size_t)(N + 1) * sizeof(int));
  int* cnt     = (int*)alloc((size_t)N * sizeof(int));
  int* tscan   = (int*)alloc((size_t)N * sizeof(int));
  int* bsum    = (int*)alloc((size_t)1024 * sizeof(int));
  int* csr_src = (int*)alloc((size_t)E * sizeof(int));
  ushort* wpk[8];
  for (int i = 0; i < 8; ++i) wpk[i] = (ushort*)alloc(128 * 128 * 2 * sizeof(ushort));
  ushort* p0hi = (ushort*)alloc((size_t)N * 128 * sizeof(ushort));
  ushort* p0lo = (ushort*)alloc((size_t)N * 128 * sizeof(ushort));
  float* bufA  = (float*)alloc((size_t)N * 128 * sizeof(float));
  float* bufB  = (float*)alloc((size_t)N * 128 * sizeof(float));
  float* bufC  = (float*)alloc((size_t)N * 128 * sizeof(float));
  ushort* m1hi = (ushort*)bufA;                 // mlp1 split out reuses bufA
  ushort* m1lo = m1hi + (size_t)N * 128;

  const int* srcp = ei;
  const int* dstp = ei + E;

  const int egrid = (E + 255) / 256;
  const int ggrid = (N + 63) / 64;
  const int agrid = (N + 3) / 4;
  const int nb = (N + 1023) / 1024;

  // CSR by dst (shared by both GAT layers)
  hipMemsetAsync(cnt, 0, (size_t)N * sizeof(int), stream);
  count_kernel<<<egrid, 256, 0, stream>>>(dstp, cnt, E);
  scan_blocks<<<nb, 1024, 0, stream>>>(cnt, tscan, bsum, N);
  scan_bsums<<<1, 1024, 0, stream>>>(bsum, rowptr, nb, N);
  scan_final<<<nb, 1024, 0, stream>>>(cnt, tscan, bsum, rowptr, N);
  hipMemsetAsync(cnt, 0, (size_t)N * sizeof(int), stream);
  fill_kernel<<<egrid, 256, 0, stream>>>(srcp, dstp, rowptr, cnt, csr_src, E);

  // Weight packs (one launch) + x split
  PackArgs pa;
  pa.w[0] = Wl1;    pa.o[0] = wpk[0]; pa.nout[0] = 128;
  pa.w[1] = Wr1;    pa.o[1] = wpk[1]; pa.nout[1] = 128;
  pa.w[2] = skip1_w;pa.o[2] = wpk[2]; pa.nout[2] = 128;
  pa.w[3] = Wl2;    pa.o[3] = wpk[3]; pa.nout[3] = 128;
  pa.w[4] = Wr2;    pa.o[4] = wpk[4]; pa.nout[4] = 128;
  pa.w[5] = skip2_w;pa.o[5] = wpk[5]; pa.nout[5] = 128;
  pa.w[6] = mlp1_w; pa.o[6] = wpk[6]; pa.nout[6] = 128;
  pa.w[7] = mlp2_w; pa.o[7] = wpk[7]; pa.nout[7] = 64;
  pack_all<<<64, 256, 0, stream>>>(pa);
  split_f32<<<(N * 128 / 4 + 255) / 256, 256, 0, stream>>>(x, p0hi, p0lo, N * 128);

  // ---- Layer 1: fused {xl1, xr1, skip1} GEMM, then agg ----
  gemm3_mfma<<<ggrid, 512, 0, stream>>>(p0hi, p0lo, wpk[0], wpk[1], wpk[2],
                                        bl1, br1, skip1_b, bufA, bufB, bufC, N);
  gat_agg<4, true><<<agrid, 256, 0, stream>>>(bufA, bufB, bufC, att1, b1,
                                              rowptr, csr_src, nullptr, p0hi, p0lo, N, 1);

  // ---- Layer 2: fused {xl2, xr2, skip2} GEMM, then agg ----
  gemm3_mfma<<<ggrid, 512, 0, stream>>>(p0hi, p0lo, wpk[3], wpk[4], wpk[5],
                                        bl2, br2, skip2_b, bufA, bufB, bufC, N);
  gat_agg<1, true><<<agrid, 256, 0, stream>>>(bufA, bufB, bufC, att2, b2,
                                              rowptr, csr_src, nullptr, p0hi, p0lo, N, 0);

  // ---- MLP head ----
  gemm_mfma<128, 1><<<ggrid, 256, 0, stream>>>(p0hi, p0lo, wpk[6], mlp1_b, nullptr, m1hi, m1lo, N);
  gemm_mfma<64, 0><<<ggrid, 256, 0, stream>>>(m1hi, m1lo, wpk[7], mlp2_b, out, nullptr, nullptr, N);
}

// Round 8
// 703.320 us; speedup vs baseline: 1.2718x; 1.0082x over previous
//
#include <hip/hip_runtime.h>

#define LEAK 0.2f

typedef __attribute__((ext_vector_type(8))) short short8v;
typedef __attribute__((ext_vector_type(4))) float float4v;

__device__ __forceinline__ ushort f2bf(float f) {
  union { float f; unsigned u; } v; v.f = f;
  unsigned r = v.u + 0x7fffu + ((v.u >> 16) & 1u);  // RNE
  return (ushort)(r >> 16);
}
__device__ __forceinline__ float bf2f(ushort h) {
  union { unsigned u; float f; } v; v.u = ((unsigned)h) << 16;
  return v.f;
}

// ---------------- CSR build (incoming edges per dst, self-loop appended) ----------------
__global__ void count_kernel(const int* __restrict__ dstp, int* __restrict__ cnt, int E) {
  int e = blockIdx.x * blockDim.x + threadIdx.x;
  if (e < E) atomicAdd(&cnt[dstp[e]], 1);
}

// scans over (cnt[i] + 1): one extra slot per node for the self-loop
__global__ __launch_bounds__(1024)
void scan_blocks(const int* __restrict__ cnt, int* __restrict__ tscan,
                 int* __restrict__ bsum, int n) {
  __shared__ int sh[1024];
  int t = threadIdx.x;
  int i = blockIdx.x * 1024 + t;
  sh[t] = (i < n) ? cnt[i] + 1 : 0;
  __syncthreads();
  for (int off = 1; off < 1024; off <<= 1) {
    int u = (t >= off) ? sh[t - off] : 0;
    __syncthreads();
    sh[t] += u;
    __syncthreads();
  }
  if (i < n) tscan[i] = sh[t];
  if (t == 1023) bsum[blockIdx.x] = sh[1023];
}

__global__ __launch_bounds__(1024)
void scan_bsums(int* __restrict__ bsum, int* __restrict__ rowptr, int nb, int n) {
  __shared__ int sh[1024];
  int t = threadIdx.x;
  sh[t] = (t < nb) ? bsum[t] : 0;
  __syncthreads();
  for (int off = 1; off < 1024; off <<= 1) {
    int u = (t >= off) ? sh[t - off] : 0;
    __syncthreads();
    sh[t] += u;
    __syncthreads();
  }
  if (t < nb) bsum[t] = sh[t];  // inclusive in place
  if (t == nb - 1) rowptr[n] = sh[t];
}

__global__ __launch_bounds__(1024)
void scan_final(const int* __restrict__ cnt, const int* __restrict__ tscan,
                const int* __restrict__ bsum, int* __restrict__ rowptr, int n) {
  int i = blockIdx.x * 1024 + threadIdx.x;
  if (i < n) {
    int bpref = (blockIdx.x == 0) ? 0 : bsum[blockIdx.x - 1];
    rowptr[i] = bpref + tscan[i] - (cnt[i] + 1);
  }
}

__global__ void fill_kernel(const int* __restrict__ srcp, const int* __restrict__ dstp,
                            const int* __restrict__ rowptr, int* __restrict__ cur,
                            int* __restrict__ csr_src, int E) {
  int e = blockIdx.x * blockDim.x + threadIdx.x;
  if (e < E) {
    int d = dstp[e];
    int pos = atomicAdd(&cur[d], 1);
    csr_src[rowptr[d] + pos] = srcp[e];
  }
}

// self-loop goes in the node's LAST slot (disjoint from fill_kernel's slots)
__global__ void self_fill(const int* __restrict__ rowptr, int* __restrict__ csr_src, int n) {
  int i = blockIdx.x * blockDim.x + threadIdx.x;
  if (i < n) csr_src[rowptr[i + 1] - 1] = i;
}

// ---------------- bf16 split helpers ----------------
__global__ void split_f32(const float* __restrict__ a, ushort* __restrict__ hi,
                          ushort* __restrict__ lo, int n) {
  int i = (blockIdx.x * blockDim.x + threadIdx.x) * 4;
  if (i >= n) return;
  float4 v = *(const float4*)(a + i);
  ushort h[4], l[4];
  float vv[4] = {v.x, v.y, v.z, v.w};
#pragma unroll
  for (int j = 0; j < 4; ++j) {
    h[j] = f2bf(vv[j]);
    l[j] = f2bf(vv[j] - bf2f(h[j]));
  }
  *(ushort4*)(hi + i) = make_ushort4(h[0], h[1], h[2], h[3]);
  *(ushort4*)(lo + i) = make_ushort4(l[0], l[1], l[2], l[3]);
}

// Pack all 8 weight matrices in ONE launch.
struct PackArgs {
  const float* w[8];
  ushort* o[8];
  int nout[8];
};
__global__ __launch_bounds__(256)
void pack_all(PackArgs pa) {
  int wsel = blockIdx.x >> 3;
  int sub = blockIdx.x & 7;
  const float* W = pa.w[wsel];
  ushort* pk = pa.o[wsel];
  int NOUT = pa.nout[wsel];
  int NT = NOUT / 16;
  int total = NT * 4 * 64;
  int t = sub * 256 + threadIdx.x;
  if (t >= total) return;
  int lane = t & 63;
  int ks = (t >> 6) & 3;
  int nt = t >> 8;
  int col = nt * 16 + (lane & 15);
  int k0 = ks * 32 + (lane >> 4) * 8;
  ushort h[8], l[8];
#pragma unroll
  for (int j = 0; j < 8; ++j) {
    float v = W[(size_t)(k0 + j) * NOUT + col];
    h[j] = f2bf(v);
    l[j] = f2bf(v - bf2f(h[j]));
  }
  size_t fb = ((size_t)(nt * 4 + ks) * 64 + lane) * 8;
  size_t fragsz = (size_t)total * 8;
#pragma unroll
  for (int j = 0; j < 8; ++j) { pk[fb + j] = h[j]; pk[fragsz + fb + j] = l[j]; }
}

// ---------- Fused triple MFMA GEMM: Cp = (Ahi+Alo) @ Wp + bp, p=0,1,2 ----------
__global__ __launch_bounds__(512)
void gemm3_mfma(const ushort* __restrict__ Ahi, const ushort* __restrict__ Alo,
                const ushort* __restrict__ W0, const ushort* __restrict__ W1,
                const ushort* __restrict__ W2,
                const float* __restrict__ b0, const float* __restrict__ b1,
                const float* __restrict__ b2,
                float* __restrict__ C0, float* __restrict__ C1, float* __restrict__ C2,
                int M) {
  int tid = threadIdx.x;
  int w = tid >> 6, lane = tid & 63;
  int l15 = lane & 15, lh = lane >> 4;
  int row0 = blockIdx.x * 64;

  const ushort* Wp[3] = {W0, W1, W2};
  const float* bp[3] = {b0, b1, b2};
  float* Cp[3] = {C0, C1, C2};

  int arow[4];
#pragma unroll
  for (int mt = 0; mt < 4; ++mt) { int rr = row0 + mt * 16 + l15; arow[mt] = rr < M ? rr : M - 1; }

  float4v acc[3][4];
#pragma unroll
  for (int p = 0; p < 3; ++p)
#pragma unroll
    for (int mt = 0; mt < 4; ++mt) {
      acc[p][mt][0] = 0.f; acc[p][mt][1] = 0.f; acc[p][mt][2] = 0.f; acc[p][mt][3] = 0.f;
    }

  const size_t fragsz = (size_t)8 * 4 * 64 * 8;  // NT=8
#pragma unroll
  for (int ks = 0; ks < 4; ++ks) {
    short8v bh[3], bl[3];
    size_t fb = ((size_t)(w * 4 + ks) * 64 + lane) * 8;
#pragma unroll
    for (int p = 0; p < 3; ++p) {
      bh[p] = *(const short8v*)(Wp[p] + fb);
      bl[p] = *(const short8v*)(Wp[p] + fragsz + fb);
    }
#pragma unroll
    for (int mt = 0; mt < 4; ++mt) {
      size_t ao = (size_t)arow[mt] * 128 + ks * 32 + lh * 8;
      short8v ah = *(const short8v*)(Ahi + ao);
      short8v al = *(const short8v*)(Alo + ao);
#pragma unroll
      for (int p = 0; p < 3; ++p) {
        acc[p][mt] = __builtin_amdgcn_mfma_f32_16x16x32_bf16(ah, bh[p], acc[p][mt], 0, 0, 0);
        acc[p][mt] = __builtin_amdgcn_mfma_f32_16x16x32_bf16(ah, bl[p], acc[p][mt], 0, 0, 0);
        acc[p][mt] = __builtin_amdgcn_mfma_f32_16x16x32_bf16(al, bh[p], acc[p][mt], 0, 0, 0);
      }
    }
  }

  int col = w * 16 + l15;
#pragma unroll
  for (int p = 0; p < 3; ++p) {
    float bb = bp[p][col];
#pragma unroll
    for (int mt = 0; mt < 4; ++mt) {
#pragma unroll
      for (int r = 0; r < 4; ++r) {
        int rr = row0 + mt * 16 + lh * 4 + r;
        if (rr < M) Cp[p][(size_t)rr * 128 + col] = acc[p][mt][r] + bb;
      }
    }
  }
}

// ---------- single MFMA GEMM (MLP head) ----------
template<int NOUT, int MODE>
__global__ __launch_bounds__(256)
void gemm_mfma(const ushort* __restrict__ Ahi, const ushort* __restrict__ Alo,
               const ushort* __restrict__ Wpk, const float* __restrict__ bias,
               float* __restrict__ Cf, ushort* __restrict__ Chi, ushort* __restrict__ Clo,
               int M) {
  constexpr int NT = NOUT / 16;
  constexpr int WNT = NT / 4;
  int tid = threadIdx.x;
  int wid = tid >> 6, lane = tid & 63;
  int l15 = lane & 15, lh = lane >> 4;
  int row0 = blockIdx.x * 64;

  int arow[4];
#pragma unroll
  for (int mt = 0; mt < 4; ++mt) { int rr = row0 + mt * 16 + l15; arow[mt] = rr < M ? rr : M - 1; }

  float4v acc[4][WNT];
#pragma unroll
  for (int mt = 0; mt < 4; ++mt)
#pragma unroll
    for (int nt2 = 0; nt2 < WNT; ++nt2) {
      acc[mt][nt2][0] = 0.f; acc[mt][nt2][1] = 0.f; acc[mt][nt2][2] = 0.f; acc[mt][nt2][3] = 0.f;
    }

  const size_t fragsz = (size_t)NT * 4 * 64 * 8;
#pragma unroll
  for (int ks = 0; ks < 4; ++ks) {
    short8v bh[WNT], bl[WNT];
#pragma unroll
    for (int nt2 = 0; nt2 < WNT; ++nt2) {
      int nt = wid * WNT + nt2;
      size_t fb = ((size_t)(nt * 4 + ks) * 64 + lane) * 8;
      bh[nt2] = *(const short8v*)(Wpk + fb);
      bl[nt2] = *(const short8v*)(Wpk + fragsz + fb);
    }
#pragma unroll
    for (int mt = 0; mt < 4; ++mt) {
      size_t ao = (size_t)arow[mt] * 128 + ks * 32 + lh * 8;
      short8v ah = *(const short8v*)(Ahi + ao);
      short8v al = *(const short8v*)(Alo + ao);
#pragma unroll
      for (int nt2 = 0; nt2 < WNT; ++nt2) {
        acc[mt][nt2] = __builtin_amdgcn_mfma_f32_16x16x32_bf16(ah, bh[nt2], acc[mt][nt2], 0, 0, 0);
        acc[mt][nt2] = __builtin_amdgcn_mfma_f32_16x16x32_bf16(ah, bl[nt2], acc[mt][nt2], 0, 0, 0);
        acc[mt][nt2] = __builtin_amdgcn_mfma_f32_16x16x32_bf16(al, bh[nt2], acc[mt][nt2], 0, 0, 0);
      }
    }
  }

#pragma unroll
  for (int mt = 0; mt < 4; ++mt) {
#pragma unroll
    for (int nt2 = 0; nt2 < WNT; ++nt2) {
      int col = (wid * WNT + nt2) * 16 + l15;
      float bb = bias[col];
#pragma unroll
      for (int r = 0; r < 4; ++r) {
        int rr = row0 + mt * 16 + lh * 4 + r;
        if (rr < M) {
          float v = acc[mt][nt2][r] + bb;
          if (MODE == 1) {
            v = fmaxf(v, 0.f);
            ushort h = f2bf(v);
            Chi[(size_t)rr * NOUT + col] = h;
            Clo[(size_t)rr * NOUT + col] = f2bf(v - bf2f(h));
          } else {
            Cf[(size_t)rr * NOUT + col] = v;
          }
        }
      }
    }
  }
}

// ---------- GATv2 aggregation: one wave per node, 2 EDGES PER WAVE ----------
// Lane layout: half = lane>>5 (which edge of the pair), sub = lane&31; each lane
// holds float4 of elems [sub*4, sub*4+4). Head group = 128/H elems = GL lanes;
// per-edge reduce is log2(GL) shfl_xor stages (within a half). Self-loop is a
// regular CSR entry (appended by self_fill), so the loop is uniform.
// Final xor-32 combines the two halves' partial sums; half 0 writes.
template<int H, bool SPLIT>
__global__ __launch_bounds__(256)
void gat_agg(const float* __restrict__ xl, const float* __restrict__ xr,
             const float* __restrict__ skip, const float* __restrict__ att,
             const float* __restrict__ gbias, const int* __restrict__ rowptr,
             const int* __restrict__ csr_src, float* __restrict__ out,
             ushort* __restrict__ outhi, ushort* __restrict__ outlo,
             int n, int relu) {
  constexpr int GL = (128 / H) / 4;  // lanes per head group: H=4 -> 8, H=1 -> 32
  int wid = blockIdx.x * (blockDim.x >> 6) + (threadIdx.x >> 6);
  if (wid >= n) return;
  int lane = threadIdx.x & 63;
  int half = lane >> 5;
  int sub = lane & 31;
  size_t base = (size_t)wid * 128 + sub * 4;
  float4 xrv = *(const float4*)(xr + base);
  float4 av = *(const float4*)(att + sub * 4);
  float ax = 0.f, ay = 0.f, az = 0.f, aw = 0.f;
  float denom = 0.f;
  int e0 = rowptr[wid], e1 = rowptr[wid + 1];

  int idx = e0 + half;
  for (; idx + 2 < e1; idx += 4) {
    int s0 = csr_src[idx], s1 = csr_src[idx + 2];
    float4 v0 = *(const float4*)(xl + (size_t)s0 * 128 + sub * 4);
    float4 v1 = *(const float4*)(xl + (size_t)s1 * 128 + sub * 4);
    float t, p0, p1;
    t = v0.x + xrv.x; t = t > 0.f ? t : LEAK * t; p0 = t * av.x;
    t = v0.y + xrv.y; t = t > 0.f ? t : LEAK * t; p0 += t * av.y;
    t = v0.z + xrv.z; t = t > 0.f ? t : LEAK * t; p0 += t * av.z;
    t = v0.w + xrv.w; t = t > 0.f ? t : LEAK * t; p0 += t * av.w;
    t = v1.x + xrv.x; t = t > 0.f ? t : LEAK * t; p1 = t * av.x;
    t = v1.y + xrv.y; t = t > 0.f ? t : LEAK * t; p1 += t * av.y;
    t = v1.z + xrv.z; t = t > 0.f ? t : LEAK * t; p1 += t * av.z;
    t = v1.w + xrv.w; t = t > 0.f ? t : LEAK * t; p1 += t * av.w;
#pragma unroll
    for (int o = 1; o < GL; o <<= 1) {
      p0 += __shfl_xor(p0, o, 64);
      p1 += __shfl_xor(p1, o, 64);
    }
    float w0 = __expf(p0), w1 = __expf(p1);
    denom += w0 + w1;
    ax += w0 * v0.x + w1 * v1.x;
    ay += w0 * v0.y + w1 * v1.y;
    az += w0 * v0.z + w1 * v1.z;
    aw += w0 * v0.w + w1 * v1.w;
  }
  for (; idx < e1; idx += 2) {
    int s0 = csr_src[idx];
    float4 v0 = *(const float4*)(xl + (size_t)s0 * 128 + sub * 4);
    float t, p0;
    t = v0.x + xrv.x; t = t > 0.f ? t : LEAK * t; p0 = t * av.x;
    t = v0.y + xrv.y; t = t > 0.f ? t : LEAK * t; p0 += t * av.y;
    t = v0.z + xrv.z; t = t > 0.f ? t : LEAK * t; p0 += t * av.z;
    t = v0.w + xrv.w; t = t > 0.f ? t : LEAK * t; p0 += t * av.w;
#pragma unroll
    for (int o = 1; o < GL; o <<= 1) p0 += __shfl_xor(p0, o, 64);
    float w0 = __expf(p0);
    denom += w0;
    ax += w0 * v0.x;
    ay += w0 * v0.y;
    az += w0 * v0.z;
    aw += w0 * v0.w;
  }

  // combine the two halves
  ax += __shfl_xor(ax, 32, 64);
  ay += __shfl_xor(ay, 32, 64);
  az += __shfl_xor(az, 32, 64);
  aw += __shfl_xor(aw, 32, 64);
  denom += __shfl_xor(denom, 32, 64);

  if (half == 0) {
    float inv = 1.f / denom;
    float4 sk = *(const float4*)(skip + base);
    float4 gb = *(const float4*)(gbias + sub * 4);
    float o0 = ax * inv + gb.x + sk.x;
    float o1 = ay * inv + gb.y + sk.y;
    float o2 = az * inv + gb.z + sk.z;
    float o3 = aw * inv + gb.w + sk.w;
    if (relu) {
      o0 = fmaxf(o0, 0.f); o1 = fmaxf(o1, 0.f);
      o2 = fmaxf(o2, 0.f); o3 = fmaxf(o3, 0.f);
    }
    if (SPLIT) {
      ushort h0 = f2bf(o0), h1 = f2bf(o1), h2 = f2bf(o2), h3 = f2bf(o3);
      *(ushort4*)(outhi + base) = make_ushort4(h0, h1, h2, h3);
      *(ushort4*)(outlo + base) = make_ushort4(f2bf(o0 - bf2f(h0)), f2bf(o1 - bf2f(h1)),
                                               f2bf(o2 - bf2f(h2)), f2bf(o3 - bf2f(h3)));
    } else {
      *(float4*)(out + base) = make_float4(o0, o1, o2, o3);
    }
  }
}

extern "C" void kernel_launch(void* const* d_in, const int* in_sizes, int n_in,
                              void* d_out, int out_size, void* d_ws, size_t ws_size,
                              hipStream_t stream) {
  const float* x       = (const float*)d_in[0];
  const int* ei        = (const int*)d_in[1];
  const float* Wl1     = (const float*)d_in[2];
  const float* bl1     = (const float*)d_in[3];
  const float* Wr1     = (const float*)d_in[4];
  const float* br1     = (const float*)d_in[5];
  const float* att1    = (const float*)d_in[6];
  const float* b1      = (const float*)d_in[7];
  const float* Wl2     = (const float*)d_in[8];
  const float* bl2     = (const float*)d_in[9];
  const float* Wr2     = (const float*)d_in[10];
  const float* br2     = (const float*)d_in[11];
  const float* att2    = (const float*)d_in[12];
  const float* b2      = (const float*)d_in[13];
  const float* skip1_w = (const float*)d_in[14];
  const float* skip1_b = (const float*)d_in[15];
  const float* skip2_w = (const float*)d_in[16];
  const float* skip2_b = (const float*)d_in[17];
  const float* mlp1_w  = (const float*)d_in[18];
  const float* mlp1_b  = (const float*)d_in[19];
  const float* mlp2_w  = (const float*)d_in[20];
  const float* mlp2_b  = (const float*)d_in[21];

  const int N = in_sizes[0] / 128;
  const int E = in_sizes[1] / 2;
  float* out = (float*)d_out;

  char* ws = (char*)d_ws;
  size_t off = 0;
  auto alloc = [&](size_t bytes) -> void* {
    void* p = ws + off;
    off = (off + bytes + 255) & ~(size_t)255;
    return p;
  };
  int* rowptr  = (int*)alloc((size_t)(N + 1) * sizeof(int));
  int* cnt     = (int*)alloc((size_t)N * sizeof(int));
  int* tscan   = (int*)alloc((size_t)N * sizeof(int));
  int* bsum    = (int*)alloc((size_t)1024 * sizeof(int));
  int* csr_src = (int*)alloc((size_t)(E + N) * sizeof(int));
  ushort* wpk[8];
  for (int i = 0; i < 8; ++i) wpk[i] = (ushort*)alloc(128 * 128 * 2 * sizeof(ushort));
  ushort* p0hi = (ushort*)alloc((size_t)N * 128 * sizeof(ushort));
  ushort* p0lo = (ushort*)alloc((size_t)N * 128 * sizeof(ushort));
  float* bufA  = (float*)alloc((size_t)N * 128 * sizeof(float));
  float* bufB  = (float*)alloc((size_t)N * 128 * sizeof(float));
  float* bufC  = (float*)alloc((size_t)N * 128 * sizeof(float));
  ushort* m1hi = (ushort*)bufA;                 // mlp1 split out reuses bufA
  ushort* m1lo = m1hi + (size_t)N * 128;

  const int* srcp = ei;
  const int* dstp = ei + E;

  const int egrid = (E + 255) / 256;
  const int ggrid = (N + 63) / 64;
  const int agrid = (N + 3) / 4;
  const int nb = (N + 1023) / 1024;

  // CSR by dst with embedded self-loops (shared by both GAT layers)
  hipMemsetAsync(cnt, 0, (size_t)N * sizeof(int), stream);
  count_kernel<<<egrid, 256, 0, stream>>>(dstp, cnt, E);
  scan_blocks<<<nb, 1024, 0, stream>>>(cnt, tscan, bsum, N);
  scan_bsums<<<1, 1024, 0, stream>>>(bsum, rowptr, nb, N);
  scan_final<<<nb, 1024, 0, stream>>>(cnt, tscan, bsum, rowptr, N);
  self_fill<<<(N + 255) / 256, 256, 0, stream>>>(rowptr, csr_src, N);
  hipMemsetAsync(cnt, 0, (size_t)N * sizeof(int), stream);
  fill_kernel<<<egrid, 256, 0, stream>>>(srcp, dstp, rowptr, cnt, csr_src, E);

  // Weight packs (one launch) + x split
  PackArgs pa;
  pa.w[0] = Wl1;    pa.o[0] = wpk[0]; pa.nout[0] = 128;
  pa.w[1] = Wr1;    pa.o[1] = wpk[1]; pa.nout[1] = 128;
  pa.w[2] = skip1_w;pa.o[2] = wpk[2]; pa.nout[2] = 128;
  pa.w[3] = Wl2;    pa.o[3] = wpk[3]; pa.nout[3] = 128;
  pa.w[4] = Wr2;    pa.o[4] = wpk[4]; pa.nout[4] = 128;
  pa.w[5] = skip2_w;pa.o[5] = wpk[5]; pa.nout[5] = 128;
  pa.w[6] = mlp1_w; pa.o[6] = wpk[6]; pa.nout[6] = 128;
  pa.w[7] = mlp2_w; pa.o[7] = wpk[7]; pa.nout[7] = 64;
  pack_all<<<64, 256, 0, stream>>>(pa);
  split_f32<<<(N * 128 / 4 + 255) / 256, 256, 0, stream>>>(x, p0hi, p0lo, N * 128);

  // ---- Layer 1: fused {xl1, xr1, skip1} GEMM, then agg ----
  gemm3_mfma<<<ggrid, 512, 0, stream>>>(p0hi, p0lo, wpk[0], wpk[1], wpk[2],
                                        bl1, br1, skip1_b, bufA, bufB, bufC, N);
  gat_agg<4, true><<<agrid, 256, 0, stream>>>(bufA, bufB, bufC, att1, b1,
                                              rowptr, csr_src, nullptr, p0hi, p0lo, N, 1);

  // ---- Layer 2: fused {xl2, xr2, skip2} GEMM, then agg ----
  gemm3_mfma<<<ggrid, 512, 0, stream>>>(p0hi, p0lo, wpk[3], wpk[4], wpk[5],
                                        bl2, br2, skip2_b, bufA, bufB, bufC, N);
  gat_agg<1, true><<<agrid, 256, 0, stream>>>(bufA, bufB, bufC, att2, b2,
                                              rowptr, csr_src, nullptr, p0hi, p0lo, N, 0);

  // ---- MLP head ----
  gemm_mfma<128, 1><<<ggrid, 256, 0, stream>>>(p0hi, p0lo, wpk[6], mlp1_b, nullptr, m1hi, m1lo, N);
  gemm_mfma<64, 0><<<ggrid, 256, 0, stream>>>(m1hi, m1lo, wpk[7], mlp2_b, out, nullptr, nullptr, N);
}

// Round 9
// 605.450 us; speedup vs baseline: 1.4774x; 1.1616x over previous
//
#include <hip/hip_runtime.h>

#define LEAK 0.2f

typedef __attribute__((ext_vector_type(8))) short short8v;
typedef __attribute__((ext_vector_type(4))) float float4v;

__device__ __forceinline__ ushort f2bf(float f) {
  union { float f; unsigned u; } v; v.f = f;
  unsigned r = v.u + 0x7fffu + ((v.u >> 16) & 1u);  // RNE
  return (ushort)(r >> 16);
}
__device__ __forceinline__ float bf2f(ushort h) {
  union { unsigned u; float f; } v; v.u = ((unsigned)h) << 16;
  return v.f;
}

// ---------------- CSR build (incoming edges per dst, self-loop appended) ----------------
__global__ void count_kernel(const int* __restrict__ dstp, int* __restrict__ cnt, int E) {
  int e = blockIdx.x * blockDim.x + threadIdx.x;
  if (e < E) atomicAdd(&cnt[dstp[e]], 1);
}

// scans over (cnt[i] + 1): one extra slot per node for the self-loop
__global__ __launch_bounds__(1024)
void scan_blocks(const int* __restrict__ cnt, int* __restrict__ tscan,
                 int* __restrict__ bsum, int n) {
  __shared__ int sh[1024];
  int t = threadIdx.x;
  int i = blockIdx.x * 1024 + t;
  sh[t] = (i < n) ? cnt[i] + 1 : 0;
  __syncthreads();
  for (int off = 1; off < 1024; off <<= 1) {
    int u = (t >= off) ? sh[t - off] : 0;
    __syncthreads();
    sh[t] += u;
    __syncthreads();
  }
  if (i < n) tscan[i] = sh[t];
  if (t == 1023) bsum[blockIdx.x] = sh[1023];
}

__global__ __launch_bounds__(1024)
void scan_bsums(int* __restrict__ bsum, int* __restrict__ rowptr, int nb, int n) {
  __shared__ int sh[1024];
  int t = threadIdx.x;
  sh[t] = (t < nb) ? bsum[t] : 0;
  __syncthreads();
  for (int off = 1; off < 1024; off <<= 1) {
    int u = (t >= off) ? sh[t - off] : 0;
    __syncthreads();
    sh[t] += u;
    __syncthreads();
  }
  if (t < nb) bsum[t] = sh[t];  // inclusive in place
  if (t == nb - 1) rowptr[n] = sh[t];
}

__global__ __launch_bounds__(1024)
void scan_final(const int* __restrict__ cnt, const int* __restrict__ tscan,
                const int* __restrict__ bsum, int* __restrict__ rowptr, int n) {
  int i = blockIdx.x * 1024 + threadIdx.x;
  if (i < n) {
    int bpref = (blockIdx.x == 0) ? 0 : bsum[blockIdx.x - 1];
    rowptr[i] = bpref + tscan[i] - (cnt[i] + 1);
  }
}

__global__ void fill_kernel(const int* __restrict__ srcp, const int* __restrict__ dstp,
                            const int* __restrict__ rowptr, int* __restrict__ cur,
                            int* __restrict__ csr_src, int E) {
  int e = blockIdx.x * blockDim.x + threadIdx.x;
  if (e < E) {
    int d = dstp[e];
    int pos = atomicAdd(&cur[d], 1);
    csr_src[rowptr[d] + pos] = srcp[e];
  }
}

// self-loop goes in the node's LAST slot (disjoint from fill_kernel's slots)
__global__ void self_fill(const int* __restrict__ rowptr, int* __restrict__ csr_src, int n) {
  int i = blockIdx.x * blockDim.x + threadIdx.x;
  if (i < n) csr_src[rowptr[i + 1] - 1] = i;
}

// ---------------- bf16 split helpers ----------------
__global__ void split_f32(const float* __restrict__ a, ushort* __restrict__ hi,
                          ushort* __restrict__ lo, int n) {
  int i = (blockIdx.x * blockDim.x + threadIdx.x) * 4;
  if (i >= n) return;
  float4 v = *(const float4*)(a + i);
  ushort h[4], l[4];
  float vv[4] = {v.x, v.y, v.z, v.w};
#pragma unroll
  for (int j = 0; j < 4; ++j) {
    h[j] = f2bf(vv[j]);
    l[j] = f2bf(vv[j] - bf2f(h[j]));
  }
  *(ushort4*)(hi + i) = make_ushort4(h[0], h[1], h[2], h[3]);
  *(ushort4*)(lo + i) = make_ushort4(l[0], l[1], l[2], l[3]);
}

// Pack all 8 weight matrices in ONE launch.
struct PackArgs {
  const float* w[8];
  ushort* o[8];
  int nout[8];
};
__global__ __launch_bounds__(256)
void pack_all(PackArgs pa) {
  int wsel = blockIdx.x >> 3;
  int sub = blockIdx.x & 7;
  const float* W = pa.w[wsel];
  ushort* pk = pa.o[wsel];
  int NOUT = pa.nout[wsel];
  int NT = NOUT / 16;
  int total = NT * 4 * 64;
  int t = sub * 256 + threadIdx.x;
  if (t >= total) return;
  int lane = t & 63;
  int ks = (t >> 6) & 3;
  int nt = t >> 8;
  int col = nt * 16 + (lane & 15);
  int k0 = ks * 32 + (lane >> 4) * 8;
  ushort h[8], l[8];
#pragma unroll
  for (int j = 0; j < 8; ++j) {
    float v = W[(size_t)(k0 + j) * NOUT + col];
    h[j] = f2bf(v);
    l[j] = f2bf(v - bf2f(h[j]));
  }
  size_t fb = ((size_t)(nt * 4 + ks) * 64 + lane) * 8;
  size_t fragsz = (size_t)total * 8;
#pragma unroll
  for (int j = 0; j < 8; ++j) { pk[fb + j] = h[j]; pk[fragsz + fb + j] = l[j]; }
}

// ---------- Fused triple MFMA GEMM: Cp = (Ahi+Alo) @ Wp + bp, p=0,1,2 ----------
// C0 (the gather operand xl) is written as SINGLE-ROUNDED bf16 (halves the agg
// gather bytes); C1, C2 stay fp32. ks-loop NOT unrolled: caps live W-fragment
// VGPRs at 24 (vs ~96 fully unrolled) to keep 4 waves/SIMD.
__global__ __launch_bounds__(512)
void gemm3_mfma(const ushort* __restrict__ Ahi, const ushort* __restrict__ Alo,
                const ushort* __restrict__ W0, const ushort* __restrict__ W1,
                const ushort* __restrict__ W2,
                const float* __restrict__ b0, const float* __restrict__ b1,
                const float* __restrict__ b2,
                ushort* __restrict__ C0b, float* __restrict__ C1, float* __restrict__ C2,
                int M) {
  int tid = threadIdx.x;
  int w = tid >> 6, lane = tid & 63;
  int l15 = lane & 15, lh = lane >> 4;
  int row0 = blockIdx.x * 64;

  const ushort* Wp[3] = {W0, W1, W2};

  int arow[4];
#pragma unroll
  for (int mt = 0; mt < 4; ++mt) { int rr = row0 + mt * 16 + l15; arow[mt] = rr < M ? rr : M - 1; }

  float4v acc[3][4];
#pragma unroll
  for (int p = 0; p < 3; ++p)
#pragma unroll
    for (int mt = 0; mt < 4; ++mt) {
      acc[p][mt][0] = 0.f; acc[p][mt][1] = 0.f; acc[p][mt][2] = 0.f; acc[p][mt][3] = 0.f;
    }

  const size_t fragsz = (size_t)8 * 4 * 64 * 8;  // NT=8
#pragma unroll 1
  for (int ks = 0; ks < 4; ++ks) {
    short8v bh[3], bl[3];
    size_t fb = ((size_t)(w * 4 + ks) * 64 + lane) * 8;
#pragma unroll
    for (int p = 0; p < 3; ++p) {
      bh[p] = *(const short8v*)(Wp[p] + fb);
      bl[p] = *(const short8v*)(Wp[p] + fragsz + fb);
    }
#pragma unroll
    for (int mt = 0; mt < 4; ++mt) {
      size_t ao = (size_t)arow[mt] * 128 + ks * 32 + lh * 8;
      short8v ah = *(const short8v*)(Ahi + ao);
      short8v al = *(const short8v*)(Alo + ao);
#pragma unroll
      for (int p = 0; p < 3; ++p) {
        acc[p][mt] = __builtin_amdgcn_mfma_f32_16x16x32_bf16(ah, bh[p], acc[p][mt], 0, 0, 0);
        acc[p][mt] = __builtin_amdgcn_mfma_f32_16x16x32_bf16(ah, bl[p], acc[p][mt], 0, 0, 0);
        acc[p][mt] = __builtin_amdgcn_mfma_f32_16x16x32_bf16(al, bh[p], acc[p][mt], 0, 0, 0);
      }
    }
  }

  int col = w * 16 + l15;
  float bb0 = b0[col], bb1 = b1[col], bb2 = b2[col];
#pragma unroll
  for (int mt = 0; mt < 4; ++mt) {
#pragma unroll
    for (int r = 0; r < 4; ++r) {
      int rr = row0 + mt * 16 + lh * 4 + r;
      if (rr < M) {
        C0b[(size_t)rr * 128 + col] = f2bf(acc[0][mt][r] + bb0);
        C1[(size_t)rr * 128 + col] = acc[1][mt][r] + bb1;
        C2[(size_t)rr * 128 + col] = acc[2][mt][r] + bb2;
      }
    }
  }
}

// ---------- single MFMA GEMM (MLP head) ----------
template<int NOUT, int MODE>
__global__ __launch_bounds__(256)
void gemm_mfma(const ushort* __restrict__ Ahi, const ushort* __restrict__ Alo,
               const ushort* __restrict__ Wpk, const float* __restrict__ bias,
               float* __restrict__ Cf, ushort* __restrict__ Chi, ushort* __restrict__ Clo,
               int M) {
  constexpr int NT = NOUT / 16;
  constexpr int WNT = NT / 4;
  int tid = threadIdx.x;
  int wid = tid >> 6, lane = tid & 63;
  int l15 = lane & 15, lh = lane >> 4;
  int row0 = blockIdx.x * 64;

  int arow[4];
#pragma unroll
  for (int mt = 0; mt < 4; ++mt) { int rr = row0 + mt * 16 + l15; arow[mt] = rr < M ? rr : M - 1; }

  float4v acc[4][WNT];
#pragma unroll
  for (int mt = 0; mt < 4; ++mt)
#pragma unroll
    for (int nt2 = 0; nt2 < WNT; ++nt2) {
      acc[mt][nt2][0] = 0.f; acc[mt][nt2][1] = 0.f; acc[mt][nt2][2] = 0.f; acc[mt][nt2][3] = 0.f;
    }

  const size_t fragsz = (size_t)NT * 4 * 64 * 8;
#pragma unroll 1
  for (int ks = 0; ks < 4; ++ks) {
    short8v bh[WNT], bl[WNT];
#pragma unroll
    for (int nt2 = 0; nt2 < WNT; ++nt2) {
      int nt = wid * WNT + nt2;
      size_t fb = ((size_t)(nt * 4 + ks) * 64 + lane) * 8;
      bh[nt2] = *(const short8v*)(Wpk + fb);
      bl[nt2] = *(const short8v*)(Wpk + fragsz + fb);
    }
#pragma unroll
    for (int mt = 0; mt < 4; ++mt) {
      size_t ao = (size_t)arow[mt] * 128 + ks * 32 + lh * 8;
      short8v ah = *(const short8v*)(Ahi + ao);
      short8v al = *(const short8v*)(Alo + ao);
#pragma unroll
      for (int nt2 = 0; nt2 < WNT; ++nt2) {
        acc[mt][nt2] = __builtin_amdgcn_mfma_f32_16x16x32_bf16(ah, bh[nt2], acc[mt][nt2], 0, 0, 0);
        acc[mt][nt2] = __builtin_amdgcn_mfma_f32_16x16x32_bf16(ah, bl[nt2], acc[mt][nt2], 0, 0, 0);
        acc[mt][nt2] = __builtin_amdgcn_mfma_f32_16x16x32_bf16(al, bh[nt2], acc[mt][nt2], 0, 0, 0);
      }
    }
  }

#pragma unroll
  for (int mt = 0; mt < 4; ++mt) {
#pragma unroll
    for (int nt2 = 0; nt2 < WNT; ++nt2) {
      int col = (wid * WNT + nt2) * 16 + l15;
      float bb = bias[col];
#pragma unroll
      for (int r = 0; r < 4; ++r) {
        int rr = row0 + mt * 16 + lh * 4 + r;
        if (rr < M) {
          float v = acc[mt][nt2][r] + bb;
          if (MODE == 1) {
            v = fmaxf(v, 0.f);
            ushort h = f2bf(v);
            Chi[(size_t)rr * NOUT + col] = h;
            Clo[(size_t)rr * NOUT + col] = f2bf(v - bf2f(h));
          } else {
            Cf[(size_t)rr * NOUT + col] = v;
          }
        }
      }
    }
  }
}

// ---------- GATv2 aggregation: one wave per node, 2 edges per wave ----------
// xl is bf16 (single-rounded): gather 256 B/row instead of 512 B. Convert via
// u<<16 / u&0xFFFF0000 (2 ops per packed pair). Self-loop is a regular CSR
// entry. Final xor-32 combines the two halves; half 0 writes.
template<int H, bool SPLIT>
__global__ __launch_bounds__(256)
void gat_agg(const ushort* __restrict__ xlb, const float* __restrict__ xr,
             const float* __restrict__ skip, const float* __restrict__ att,
             const float* __restrict__ gbias, const int* __restrict__ rowptr,
             const int* __restrict__ csr_src, float* __restrict__ out,
             ushort* __restrict__ outhi, ushort* __restrict__ outlo,
             int n, int relu) {
  constexpr int GL = (128 / H) / 4;  // lanes per head group: H=4 -> 8, H=1 -> 32
  int wid = blockIdx.x * (blockDim.x >> 6) + (threadIdx.x >> 6);
  if (wid >= n) return;
  int lane = threadIdx.x & 63;
  int half = lane >> 5;
  int sub = lane & 31;
  size_t base = (size_t)wid * 128 + sub * 4;
  float4 xrv = *(const float4*)(xr + base);
  float4 av = *(const float4*)(att + sub * 4);
  float ax = 0.f, ay = 0.f, az = 0.f, aw = 0.f;
  float denom = 0.f;
  int e0 = rowptr[wid], e1 = rowptr[wid + 1];

  int idx = e0 + half;
  for (; idx + 2 < e1; idx += 4) {
    int s0 = csr_src[idx], s1 = csr_src[idx + 2];
    uint2 u0 = *(const uint2*)(xlb + (size_t)s0 * 128 + sub * 4);
    uint2 u1 = *(const uint2*)(xlb + (size_t)s1 * 128 + sub * 4);
    float4 v0, v1;
    v0.x = __uint_as_float(u0.x << 16); v0.y = __uint_as_float(u0.x & 0xFFFF0000u);
    v0.z = __uint_as_float(u0.y << 16); v0.w = __uint_as_float(u0.y & 0xFFFF0000u);
    v1.x = __uint_as_float(u1.x << 16); v1.y = __uint_as_float(u1.x & 0xFFFF0000u);
    v1.z = __uint_as_float(u1.y << 16); v1.w = __uint_as_float(u1.y & 0xFFFF0000u);
    float t, p0, p1;
    t = v0.x + xrv.x; t = t > 0.f ? t : LEAK * t; p0 = t * av.x;
    t = v0.y + xrv.y; t = t > 0.f ? t : LEAK * t; p0 += t * av.y;
    t = v0.z + xrv.z; t = t > 0.f ? t : LEAK * t; p0 += t * av.z;
    t = v0.w + xrv.w; t = t > 0.f ? t : LEAK * t; p0 += t * av.w;
    t = v1.x + xrv.x; t = t > 0.f ? t : LEAK * t; p1 = t * av.x;
    t = v1.y + xrv.y; t = t > 0.f ? t : LEAK * t; p1 += t * av.y;
    t = v1.z + xrv.z; t = t > 0.f ? t : LEAK * t; p1 += t * av.z;
    t = v1.w + xrv.w; t = t > 0.f ? t : LEAK * t; p1 += t * av.w;
#pragma unroll
    for (int o = 1; o < GL; o <<= 1) {
      p0 += __shfl_xor(p0, o, 64);
      p1 += __shfl_xor(p1, o, 64);
    }
    float w0 = __expf(p0), w1 = __expf(p1);
    denom += w0 + w1;
    ax += w0 * v0.x + w1 * v1.x;
    ay += w0 * v0.y + w1 * v1.y;
    az += w0 * v0.z + w1 * v1.z;
    aw += w0 * v0.w + w1 * v1.w;
  }
  for (; idx < e1; idx += 2) {
    int s0 = csr_src[idx];
    uint2 u0 = *(const uint2*)(xlb + (size_t)s0 * 128 + sub * 4);
    float4 v0;
    v0.x = __uint_as_float(u0.x << 16); v0.y = __uint_as_float(u0.x & 0xFFFF0000u);
    v0.z = __uint_as_float(u0.y << 16); v0.w = __uint_as_float(u0.y & 0xFFFF0000u);
    float t, p0;
    t = v0.x + xrv.x; t = t > 0.f ? t : LEAK * t; p0 = t * av.x;
    t = v0.y + xrv.y; t = t > 0.f ? t : LEAK * t; p0 += t * av.y;
    t = v0.z + xrv.z; t = t > 0.f ? t : LEAK * t; p0 += t * av.z;
    t = v0.w + xrv.w; t = t > 0.f ? t : LEAK * t; p0 += t * av.w;
#pragma unroll
    for (int o = 1; o < GL; o <<= 1) p0 += __shfl_xor(p0, o, 64);
    float w0 = __expf(p0);
    denom += w0;
    ax += w0 * v0.x;
    ay += w0 * v0.y;
    az += w0 * v0.z;
    aw += w0 * v0.w;
  }

  // combine the two halves
  ax += __shfl_xor(ax, 32, 64);
  ay += __shfl_xor(ay, 32, 64);
  az += __shfl_xor(az, 32, 64);
  aw += __shfl_xor(aw, 32, 64);
  denom += __shfl_xor(denom, 32, 64);

  if (half == 0) {
    float inv = 1.f / denom;
    float4 sk = *(const float4*)(skip + base);
    float4 gb = *(const float4*)(gbias + sub * 4);
    float o0 = ax * inv + gb.x + sk.x;
    float o1 = ay * inv + gb.y + sk.y;
    float o2 = az * inv + gb.z + sk.z;
    float o3 = aw * inv + gb.w + sk.w;
    if (relu) {
      o0 = fmaxf(o0, 0.f); o1 = fmaxf(o1, 0.f);
      o2 = fmaxf(o2, 0.f); o3 = fmaxf(o3, 0.f);
    }
    if (SPLIT) {
      ushort h0 = f2bf(o0), h1 = f2bf(o1), h2 = f2bf(o2), h3 = f2bf(o3);
      *(ushort4*)(outhi + base) = make_ushort4(h0, h1, h2, h3);
      *(ushort4*)(outlo + base) = make_ushort4(f2bf(o0 - bf2f(h0)), f2bf(o1 - bf2f(h1)),
                                               f2bf(o2 - bf2f(h2)), f2bf(o3 - bf2f(h3)));
    } else {
      *(float4*)(out + base) = make_float4(o0, o1, o2, o3);
    }
  }
}

extern "C" void kernel_launch(void* const* d_in, const int* in_sizes, int n_in,
                              void* d_out, int out_size, void* d_ws, size_t ws_size,
                              hipStream_t stream) {
  const float* x       = (const float*)d_in[0];
  const int* ei        = (const int*)d_in[1];
  const float* Wl1     = (const float*)d_in[2];
  const float* bl1     = (const float*)d_in[3];
  const float* Wr1     = (const float*)d_in[4];
  const float* br1     = (const float*)d_in[5];
  const float* att1    = (const float*)d_in[6];
  const float* b1      = (const float*)d_in[7];
  const float* Wl2     = (const float*)d_in[8];
  const float* bl2     = (const float*)d_in[9];
  const float* Wr2     = (const float*)d_in[10];
  const float* br2     = (const float*)d_in[11];
  const float* att2    = (const float*)d_in[12];
  const float* b2      = (const float*)d_in[13];
  const float* skip1_w = (const float*)d_in[14];
  const float* skip1_b = (const float*)d_in[15];
  const float* skip2_w = (const float*)d_in[16];
  const float* skip2_b = (const float*)d_in[17];
  const float* mlp1_w  = (const float*)d_in[18];
  const float* mlp1_b  = (const float*)d_in[19];
  const float* mlp2_w  = (const float*)d_in[20];
  const float* mlp2_b  = (const float*)d_in[21];

  const int N = in_sizes[0] / 128;
  const int E = in_sizes[1] / 2;
  float* out = (float*)d_out;

  char* ws = (char*)d_ws;
  size_t off = 0;
  auto alloc = [&](size_t bytes) -> void* {
    void* p = ws + off;
    off = (off + bytes + 255) & ~(size_t)255;
    return p;
  };
  int* rowptr  = (int*)alloc((size_t)(N + 1) * sizeof(int));
  int* cnt     = (int*)alloc((size_t)N * sizeof(int));
  int* tscan   = (int*)alloc((size_t)N * sizeof(int));
  int* bsum    = (int*)alloc((size_t)1024 * sizeof(int));
  int* csr_src = (int*)alloc((size_t)(E + N) * sizeof(int));
  ushort* wpk[8];
  for (int i = 0; i < 8; ++i) wpk[i] = (ushort*)alloc(128 * 128 * 2 * sizeof(ushort));
  ushort* p0hi = (ushort*)alloc((size_t)N * 128 * sizeof(ushort));
  ushort* p0lo = (ushort*)alloc((size_t)N * 128 * sizeof(ushort));
  float* bufA  = (float*)alloc((size_t)N * 128 * sizeof(float));  // xlb (ushort) / m1hi+m1lo
  float* bufB  = (float*)alloc((size_t)N * 128 * sizeof(float));
  float* bufC  = (float*)alloc((size_t)N * 128 * sizeof(float));
  ushort* xlb  = (ushort*)bufA;                 // bf16 xl operand for agg
  ushort* m1hi = (ushort*)bufA;                 // mlp1 split out reuses bufA
  ushort* m1lo = m1hi + (size_t)N * 128;

  const int* srcp = ei;
  const int* dstp = ei + E;

  const int egrid = (E + 255) / 256;
  const int ggrid = (N + 63) / 64;
  const int agrid = (N + 3) / 4;
  const int nb = (N + 1023) / 1024;

  // CSR by dst with embedded self-loops (shared by both GAT layers)
  hipMemsetAsync(cnt, 0, (size_t)N * sizeof(int), stream);
  count_kernel<<<egrid, 256, 0, stream>>>(dstp, cnt, E);
  scan_blocks<<<nb, 1024, 0, stream>>>(cnt, tscan, bsum, N);
  scan_bsums<<<1, 1024, 0, stream>>>(bsum, rowptr, nb, N);
  scan_final<<<nb, 1024, 0, stream>>>(cnt, tscan, bsum, rowptr, N);
  self_fill<<<(N + 255) / 256, 256, 0, stream>>>(rowptr, csr_src, N);
  hipMemsetAsync(cnt, 0, (size_t)N * sizeof(int), stream);
  fill_kernel<<<egrid, 256, 0, stream>>>(srcp, dstp, rowptr, cnt, csr_src, E);

  // Weight packs (one launch) + x split
  PackArgs pa;
  pa.w[0] = Wl1;    pa.o[0] = wpk[0]; pa.nout[0] = 128;
  pa.w[1] = Wr1;    pa.o[1] = wpk[1]; pa.nout[1] = 128;
  pa.w[2] = skip1_w;pa.o[2] = wpk[2]; pa.nout[2] = 128;
  pa.w[3] = Wl2;    pa.o[3] = wpk[3]; pa.nout[3] = 128;
  pa.w[4] = Wr2;    pa.o[4] = wpk[4]; pa.nout[4] = 128;
  pa.w[5] = skip2_w;pa.o[5] = wpk[5]; pa.nout[5] = 128;
  pa.w[6] = mlp1_w; pa.o[6] = wpk[6]; pa.nout[6] = 128;
  pa.w[7] = mlp2_w; pa.o[7] = wpk[7]; pa.nout[7] = 64;
  pack_all<<<64, 256, 0, stream>>>(pa);
  split_f32<<<(N * 128 / 4 + 255) / 256, 256, 0, stream>>>(x, p0hi, p0lo, N * 128);

  // ---- Layer 1: fused {xl1(bf16), xr1, skip1} GEMM, then agg ----
  gemm3_mfma<<<ggrid, 512, 0, stream>>>(p0hi, p0lo, wpk[0], wpk[1], wpk[2],
                                        bl1, br1, skip1_b, xlb, bufB, bufC, N);
  gat_agg<4, true><<<agrid, 256, 0, stream>>>(xlb, bufB, bufC, att1, b1,
                                              rowptr, csr_src, nullptr, p0hi, p0lo, N, 1);

  // ---- Layer 2: fused {xl2(bf16), xr2, skip2} GEMM, then agg ----
  gemm3_mfma<<<ggrid, 512, 0, stream>>>(p0hi, p0lo, wpk[3], wpk[4], wpk[5],
                                        bl2, br2, skip2_b, xlb, bufB, bufC, N);
  gat_agg<1, true><<<agrid, 256, 0, stream>>>(xlb, bufB, bufC, att2, b2,
                                              rowptr, csr_src, nullptr, p0hi, p0lo, N, 0);

  // ---- MLP head ----
  gemm_mfma<128, 1><<<ggrid, 256, 0, stream>>>(p0hi, p0lo, wpk[6], mlp1_b, nullptr, m1hi, m1lo, N);
  gemm_mfma<64, 0><<<ggrid, 256, 0, stream>>>(m1hi, m1lo, wpk[7], mlp2_b, out, nullptr, nullptr, N);
}

// Round 10
// 590.759 us; speedup vs baseline: 1.5141x; 1.0249x over previous
//
#include <hip/hip_runtime.h>

#define LEAK 0.2f

typedef __attribute__((ext_vector_type(8))) short short8v;
typedef __attribute__((ext_vector_type(4))) float float4v;

__device__ __forceinline__ ushort f2bf(float f) {
  union { float f; unsigned u; } v; v.f = f;
  unsigned r = v.u + 0x7fffu + ((v.u >> 16) & 1u);  // RNE
  return (ushort)(r >> 16);
}
__device__ __forceinline__ float bf2f(ushort h) {
  union { unsigned u; float f; } v; v.u = ((unsigned)h) << 16;
  return v.f;
}
// leaky_relu(t, 0.2) = 0.6t + 0.4|t|  (2 VALU: mul + fma-with-abs)
__device__ __forceinline__ float lrelu(float t) {
  return fmaf(0.4f, fabsf(t), 0.6f * t);
}

// ---------------- CSR build (incoming edges per dst, self-loop appended) ----------------
__global__ void count_kernel(const int* __restrict__ dstp, int* __restrict__ cnt, int E) {
  int e = blockIdx.x * blockDim.x + threadIdx.x;
  if (e < E) atomicAdd(&cnt[dstp[e]], 1);
}

// per-1024-block inclusive scan over (cnt[i]+1); raw block sums to bsum
__global__ __launch_bounds__(1024)
void scan_blocks(const int* __restrict__ cnt, int* __restrict__ tscan,
                 int* __restrict__ bsum, int n) {
  __shared__ int sh[1024];
  int t = threadIdx.x;
  int i = blockIdx.x * 1024 + t;
  sh[t] = (i < n) ? cnt[i] + 1 : 0;
  __syncthreads();
  for (int off = 1; off < 1024; off <<= 1) {
    int u = (t >= off) ? sh[t - off] : 0;
    __syncthreads();
    sh[t] += u;
    __syncthreads();
  }
  if (i < n) tscan[i] = sh[t];
  if (t == 1023) bsum[blockIdx.x] = sh[1023];
}

// fused: local scan of raw bsum + rowptr + self-loop slot + cur-zeroing + total
__global__ __launch_bounds__(1024)
void scan_final(int* __restrict__ cnt, const int* __restrict__ tscan,
                const int* __restrict__ bsum, int* __restrict__ rowptr,
                int* __restrict__ csr_src, int n, int nb) {
  __shared__ int sh[1024];
  int t = threadIdx.x;
  sh[t] = (t < nb) ? bsum[t] : 0;
  __syncthreads();
  for (int off = 1; off < 1024; off <<= 1) {
    int u = (t >= off) ? sh[t - off] : 0;
    __syncthreads();
    sh[t] += u;
    __syncthreads();
  }
  int i = blockIdx.x * 1024 + t;
  if (i < n) {
    int bpref = (blockIdx.x == 0) ? 0 : sh[blockIdx.x - 1];
    int incl = bpref + tscan[i];          // inclusive scan of (cnt+1)
    rowptr[i] = incl - (cnt[i] + 1);
    csr_src[incl - 1] = i;                // self-loop in node's LAST slot
    cnt[i] = 0;                           // becomes `cur` for fill_kernel
  }
  if (blockIdx.x == nb - 1 && t == 0) rowptr[n] = sh[nb - 1];
}

__global__ void fill_kernel(const int* __restrict__ srcp, const int* __restrict__ dstp,
                            const int* __restrict__ rowptr, int* __restrict__ cur,
                            int* __restrict__ csr_src, int E) {
  int e = blockIdx.x * blockDim.x + threadIdx.x;
  if (e < E) {
    int d = dstp[e];
    int pos = atomicAdd(&cur[d], 1);
    csr_src[rowptr[d] + pos] = srcp[e];
  }
}

// ---------------- bf16 split helpers ----------------
__global__ void split_f32(const float* __restrict__ a, ushort* __restrict__ hi,
                          ushort* __restrict__ lo, int n) {
  int i = (blockIdx.x * blockDim.x + threadIdx.x) * 4;
  if (i >= n) return;
  float4 v = *(const float4*)(a + i);
  ushort h[4], l[4];
  float vv[4] = {v.x, v.y, v.z, v.w};
#pragma unroll
  for (int j = 0; j < 4; ++j) {
    h[j] = f2bf(vv[j]);
    l[j] = f2bf(vv[j] - bf2f(h[j]));
  }
  *(ushort4*)(hi + i) = make_ushort4(h[0], h[1], h[2], h[3]);
  *(ushort4*)(lo + i) = make_ushort4(l[0], l[1], l[2], l[3]);
}

// Pack all 8 weight matrices in ONE launch.
struct PackArgs {
  const float* w[8];
  ushort* o[8];
  int nout[8];
};
__global__ __launch_bounds__(256)
void pack_all(PackArgs pa) {
  int wsel = blockIdx.x >> 3;
  int sub = blockIdx.x & 7;
  const float* W = pa.w[wsel];
  ushort* pk = pa.o[wsel];
  int NOUT = pa.nout[wsel];
  int NT = NOUT / 16;
  int total = NT * 4 * 64;
  int t = sub * 256 + threadIdx.x;
  if (t >= total) return;
  int lane = t & 63;
  int ks = (t >> 6) & 3;
  int nt = t >> 8;
  int col = nt * 16 + (lane & 15);
  int k0 = ks * 32 + (lane >> 4) * 8;
  ushort h[8], l[8];
#pragma unroll
  for (int j = 0; j < 8; ++j) {
    float v = W[(size_t)(k0 + j) * NOUT + col];
    h[j] = f2bf(v);
    l[j] = f2bf(v - bf2f(h[j]));
  }
  size_t fb = ((size_t)(nt * 4 + ks) * 64 + lane) * 8;
  size_t fragsz = (size_t)total * 8;
#pragma unroll
  for (int j = 0; j < 8; ++j) { pk[fb + j] = h[j]; pk[fragsz + fb + j] = l[j]; }
}

// ---------- Fused triple MFMA GEMM: C0,C1 bf16; C2 fp32 ----------
__global__ __launch_bounds__(512)
void gemm3_mfma(const ushort* __restrict__ Ahi, const ushort* __restrict__ Alo,
                const ushort* __restrict__ W0, const ushort* __restrict__ W1,
                const ushort* __restrict__ W2,
                const float* __restrict__ b0, const float* __restrict__ b1,
                const float* __restrict__ b2,
                ushort* __restrict__ C0b, ushort* __restrict__ C1b,
                float* __restrict__ C2, int M) {
  int tid = threadIdx.x;
  int w = tid >> 6, lane = tid & 63;
  int l15 = lane & 15, lh = lane >> 4;
  int row0 = blockIdx.x * 64;

  const ushort* Wp[3] = {W0, W1, W2};

  int arow[4];
#pragma unroll
  for (int mt = 0; mt < 4; ++mt) { int rr = row0 + mt * 16 + l15; arow[mt] = rr < M ? rr : M - 1; }

  float4v acc[3][4];
#pragma unroll
  for (int p = 0; p < 3; ++p)
#pragma unroll
    for (int mt = 0; mt < 4; ++mt) {
      acc[p][mt][0] = 0.f; acc[p][mt][1] = 0.f; acc[p][mt][2] = 0.f; acc[p][mt][3] = 0.f;
    }

  const size_t fragsz = (size_t)8 * 4 * 64 * 8;  // NT=8
#pragma unroll 1
  for (int ks = 0; ks < 4; ++ks) {
    short8v bh[3], bl[3];
    size_t fb = ((size_t)(w * 4 + ks) * 64 + lane) * 8;
#pragma unroll
    for (int p = 0; p < 3; ++p) {
      bh[p] = *(const short8v*)(Wp[p] + fb);
      bl[p] = *(const short8v*)(Wp[p] + fragsz + fb);
    }
#pragma unroll
    for (int mt = 0; mt < 4; ++mt) {
      size_t ao = (size_t)arow[mt] * 128 + ks * 32 + lh * 8;
      short8v ah = *(const short8v*)(Ahi + ao);
      short8v al = *(const short8v*)(Alo + ao);
#pragma unroll
      for (int p = 0; p < 3; ++p) {
        acc[p][mt] = __builtin_amdgcn_mfma_f32_16x16x32_bf16(ah, bh[p], acc[p][mt], 0, 0, 0);
        acc[p][mt] = __builtin_amdgcn_mfma_f32_16x16x32_bf16(ah, bl[p], acc[p][mt], 0, 0, 0);
        acc[p][mt] = __builtin_amdgcn_mfma_f32_16x16x32_bf16(al, bh[p], acc[p][mt], 0, 0, 0);
      }
    }
  }

  int col = w * 16 + l15;
  float bb0 = b0[col], bb1 = b1[col], bb2 = b2[col];
#pragma unroll
  for (int mt = 0; mt < 4; ++mt) {
#pragma unroll
    for (int r = 0; r < 4; ++r) {
      int rr = row0 + mt * 16 + lh * 4 + r;
      if (rr < M) {
        C0b[(size_t)rr * 128 + col] = f2bf(acc[0][mt][r] + bb0);
        C1b[(size_t)rr * 128 + col] = f2bf(acc[1][mt][r] + bb1);
        C2[(size_t)rr * 128 + col] = acc[2][mt][r] + bb2;
      }
    }
  }
}

// ---------- Fused MLP head: out = relu(A@W1+b1) @ W2 + b2 ----------
// 256 thr = 4 waves, 64-row tile. Stage 1: wave w computes nt={2w,2w+1} of
// mlp1 (128 cols), relu+split -> LDS in k-major frag layout [2][16][64][8]
// (16B-aligned ds_read_b128, 2-way bank alias only). Stage 2: wave w computes
// nt=w of mlp2 (64 cols) reading A-frags from LDS.
__global__ __launch_bounds__(256)
void mlp_fused(const ushort* __restrict__ Ahi, const ushort* __restrict__ Alo,
               const ushort* __restrict__ W1pk, const float* __restrict__ b1,
               const ushort* __restrict__ W2pk, const float* __restrict__ b2,
               float* __restrict__ out, int M) {
  __shared__ ushort m1[2][16][64][8];   // [hi/lo][k>>3][row][k&7]
  int tid = threadIdx.x;
  int w = tid >> 6, lane = tid & 63;
  int l15 = lane & 15, lh = lane >> 4;
  int row0 = blockIdx.x * 64;

  int arow[4];
#pragma unroll
  for (int mt = 0; mt < 4; ++mt) { int rr = row0 + mt * 16 + l15; arow[mt] = rr < M ? rr : M - 1; }

  // ---- stage 1: mlp1 (NT=8, WNT=2) ----
  float4v acc1[4][2];
#pragma unroll
  for (int mt = 0; mt < 4; ++mt)
#pragma unroll
    for (int j = 0; j < 2; ++j) {
      acc1[mt][j][0] = 0.f; acc1[mt][j][1] = 0.f; acc1[mt][j][2] = 0.f; acc1[mt][j][3] = 0.f;
    }
  const size_t fragsz1 = (size_t)8 * 4 * 64 * 8;
#pragma unroll 1
  for (int ks = 0; ks < 4; ++ks) {
    short8v bh[2], bl[2];
#pragma unroll
    for (int nt2 = 0; nt2 < 2; ++nt2) {
      size_t fb = ((size_t)((w * 2 + nt2) * 4 + ks) * 64 + lane) * 8;
      bh[nt2] = *(const short8v*)(W1pk + fb);
      bl[nt2] = *(const short8v*)(W1pk + fragsz1 + fb);
    }
#pragma unroll
    for (int mt = 0; mt < 4; ++mt) {
      size_t ao = (size_t)arow[mt] * 128 + ks * 32 + lh * 8;
      short8v ah = *(const short8v*)(Ahi + ao);
      short8v al = *(const short8v*)(Alo + ao);
#pragma unroll
      for (int nt2 = 0; nt2 < 2; ++nt2) {
        acc1[mt][nt2] = __builtin_amdgcn_mfma_f32_16x16x32_bf16(ah, bh[nt2], acc1[mt][nt2], 0, 0, 0);
        acc1[mt][nt2] = __builtin_amdgcn_mfma_f32_16x16x32_bf16(ah, bl[nt2], acc1[mt][nt2], 0, 0, 0);
        acc1[mt][nt2] = __builtin_amdgcn_mfma_f32_16x16x32_bf16(al, bh[nt2], acc1[mt][nt2], 0, 0, 0);
      }
    }
  }
  // relu + split -> LDS
#pragma unroll
  for (int nt2 = 0; nt2 < 2; ++nt2) {
    int col = (w * 2 + nt2) * 16 + l15;
    float bb = b1[col];
    int kf = col >> 3, kr = col & 7;
#pragma unroll
    for (int mt = 0; mt < 4; ++mt) {
#pragma unroll
      for (int r = 0; r < 4; ++r) {
        int row = mt * 16 + lh * 4 + r;
        float v = fmaxf(acc1[mt][nt2][r] + bb, 0.f);
        ushort h = f2bf(v);
        m1[0][kf][row][kr] = h;
        m1[1][kf][row][kr] = f2bf(v - bf2f(h));
      }
    }
  }
  __syncthreads();

  // ---- stage 2: mlp2 (NT=4, wave w -> nt=w) ----
  float4v acc2[4];
#pragma unroll
  for (int mt = 0; mt < 4; ++mt) {
    acc2[mt][0] = 0.f; acc2[mt][1] = 0.f; acc2[mt][2] = 0.f; acc2[mt][3] = 0.f;
  }
  const size_t fragsz2 = (size_t)4 * 4 * 64 * 8;
#pragma unroll 1
  for (int ks = 0; ks < 4; ++ks) {
    size_t fb = ((size_t)(w * 4 + ks) * 64 + lane) * 8;
    short8v bh = *(const short8v*)(W2pk + fb);
    short8v bl = *(const short8v*)(W2pk + fragsz2 + fb);
#pragma unroll
    for (int mt = 0; mt < 4; ++mt) {
      int row = mt * 16 + l15;
      short8v ah = *(const short8v*)&m1[0][ks * 4 + lh][row][0];
      short8v al = *(const short8v*)&m1[1][ks * 4 + lh][row][0];
      acc2[mt] = __builtin_amdgcn_mfma_f32_16x16x32_bf16(ah, bh, acc2[mt], 0, 0, 0);
      acc2[mt] = __builtin_amdgcn_mfma_f32_16x16x32_bf16(ah, bl, acc2[mt], 0, 0, 0);
      acc2[mt] = __builtin_amdgcn_mfma_f32_16x16x32_bf16(al, bh, acc2[mt], 0, 0, 0);
    }
  }
  int col = w * 16 + l15;
  float bb = b2[col];
#pragma unroll
  for (int mt = 0; mt < 4; ++mt) {
#pragma unroll
    for (int r = 0; r < 4; ++r) {
      int rr = row0 + mt * 16 + lh * 4 + r;
      if (rr < M) out[(size_t)rr * 64 + col] = acc2[mt][r] + bb;
    }
  }
}

// ---------- GATv2 aggregation: one wave per node, 2 edges per wave ----------
// xl AND xr are bf16. Self-loop is a regular CSR entry. leaky = mul+fma(|t|).
template<int H, bool SPLIT>
__global__ __launch_bounds__(256)
void gat_agg(const ushort* __restrict__ xlb, const ushort* __restrict__ xrb,
             const float* __restrict__ skip, const float* __restrict__ att,
             const float* __restrict__ gbias, const int* __restrict__ rowptr,
             const int* __restrict__ csr_src, float* __restrict__ out,
             ushort* __restrict__ outhi, ushort* __restrict__ outlo,
             int n, int relu) {
  constexpr int GL = (128 / H) / 4;  // lanes per head group: H=4 -> 8, H=1 -> 32
  int wid = blockIdx.x * (blockDim.x >> 6) + (threadIdx.x >> 6);
  if (wid >= n) return;
  int lane = threadIdx.x & 63;
  int half = lane >> 5;
  int sub = lane & 31;
  size_t base = (size_t)wid * 128 + sub * 4;
  uint2 ur = *(const uint2*)(xrb + base);
  float4 xrv;
  xrv.x = __uint_as_float(ur.x << 16); xrv.y = __uint_as_float(ur.x & 0xFFFF0000u);
  xrv.z = __uint_as_float(ur.y << 16); xrv.w = __uint_as_float(ur.y & 0xFFFF0000u);
  float4 av = *(const float4*)(att + sub * 4);
  float ax = 0.f, ay = 0.f, az = 0.f, aw = 0.f;
  float denom = 0.f;
  int e0 = rowptr[wid], e1 = rowptr[wid + 1];

  int idx = e0 + half;
  for (; idx + 2 < e1; idx += 4) {
    int s0 = csr_src[idx], s1 = csr_src[idx + 2];
    uint2 u0 = *(const uint2*)(xlb + (size_t)s0 * 128 + sub * 4);
    uint2 u1 = *(const uint2*)(xlb + (size_t)s1 * 128 + sub * 4);
    float4 v0, v1;
    v0.x = __uint_as_float(u0.x << 16); v0.y = __uint_as_float(u0.x & 0xFFFF0000u);
    v0.z = __uint_as_float(u0.y << 16); v0.w = __uint_as_float(u0.y & 0xFFFF0000u);
    v1.x = __uint_as_float(u1.x << 16); v1.y = __uint_as_float(u1.x & 0xFFFF0000u);
    v1.z = __uint_as_float(u1.y << 16); v1.w = __uint_as_float(u1.y & 0xFFFF0000u);
    float p0, p1;
    p0 = lrelu(v0.x + xrv.x) * av.x;
    p0 += lrelu(v0.y + xrv.y) * av.y;
    p0 += lrelu(v0.z + xrv.z) * av.z;
    p0 += lrelu(v0.w + xrv.w) * av.w;
    p1 = lrelu(v1.x + xrv.x) * av.x;
    p1 += lrelu(v1.y + xrv.y) * av.y;
    p1 += lrelu(v1.z + xrv.z) * av.z;
    p1 += lrelu(v1.w + xrv.w) * av.w;
#pragma unroll
    for (int o = 1; o < GL; o <<= 1) {
      p0 += __shfl_xor(p0, o, 64);
      p1 += __shfl_xor(p1, o, 64);
    }
    float w0 = __expf(p0), w1 = __expf(p1);
    denom += w0 + w1;
    ax += w0 * v0.x + w1 * v1.x;
    ay += w0 * v0.y + w1 * v1.y;
    az += w0 * v0.z + w1 * v1.z;
    aw += w0 * v0.w + w1 * v1.w;
  }
  for (; idx < e1; idx += 2) {
    int s0 = csr_src[idx];
    uint2 u0 = *(const uint2*)(xlb + (size_t)s0 * 128 + sub * 4);
    float4 v0;
    v0.x = __uint_as_float(u0.x << 16); v0.y = __uint_as_float(u0.x & 0xFFFF0000u);
    v0.z = __uint_as_float(u0.y << 16); v0.w = __uint_as_float(u0.y & 0xFFFF0000u);
    float p0;
    p0 = lrelu(v0.x + xrv.x) * av.x;
    p0 += lrelu(v0.y + xrv.y) * av.y;
    p0 += lrelu(v0.z + xrv.z) * av.z;
    p0 += lrelu(v0.w + xrv.w) * av.w;
#pragma unroll
    for (int o = 1; o < GL; o <<= 1) p0 += __shfl_xor(p0, o, 64);
    float w0 = __expf(p0);
    denom += w0;
    ax += w0 * v0.x;
    ay += w0 * v0.y;
    az += w0 * v0.z;
    aw += w0 * v0.w;
  }

  // combine the two halves
  ax += __shfl_xor(ax, 32, 64);
  ay += __shfl_xor(ay, 32, 64);
  az += __shfl_xor(az, 32, 64);
  aw += __shfl_xor(aw, 32, 64);
  denom += __shfl_xor(denom, 32, 64);

  if (half == 0) {
    float inv = 1.f / denom;
    float4 sk = *(const float4*)(skip + base);
    float4 gb = *(const float4*)(gbias + sub * 4);
    float o0 = ax * inv + gb.x + sk.x;
    float o1 = ay * inv + gb.y + sk.y;
    float o2 = az * inv + gb.z + sk.z;
    float o3 = aw * inv + gb.w + sk.w;
    if (relu) {
      o0 = fmaxf(o0, 0.f); o1 = fmaxf(o1, 0.f);
      o2 = fmaxf(o2, 0.f); o3 = fmaxf(o3, 0.f);
    }
    if (SPLIT) {
      ushort h0 = f2bf(o0), h1 = f2bf(o1), h2 = f2bf(o2), h3 = f2bf(o3);
      *(ushort4*)(outhi + base) = make_ushort4(h0, h1, h2, h3);
      *(ushort4*)(outlo + base) = make_ushort4(f2bf(o0 - bf2f(h0)), f2bf(o1 - bf2f(h1)),
                                               f2bf(o2 - bf2f(h2)), f2bf(o3 - bf2f(h3)));
    } else {
      *(float4*)(out + base) = make_float4(o0, o1, o2, o3);
    }
  }
}

extern "C" void kernel_launch(void* const* d_in, const int* in_sizes, int n_in,
                              void* d_out, int out_size, void* d_ws, size_t ws_size,
                              hipStream_t stream) {
  const float* x       = (const float*)d_in[0];
  const int* ei        = (const int*)d_in[1];
  const float* Wl1     = (const float*)d_in[2];
  const float* bl1     = (const float*)d_in[3];
  const float* Wr1     = (const float*)d_in[4];
  const float* br1     = (const float*)d_in[5];
  const float* att1    = (const float*)d_in[6];
  const float* b1      = (const float*)d_in[7];
  const float* Wl2     = (const float*)d_in[8];
  const float* bl2     = (const float*)d_in[9];
  const float* Wr2     = (const float*)d_in[10];
  const float* br2     = (const float*)d_in[11];
  const float* att2    = (const float*)d_in[12];
  const float* b2      = (const float*)d_in[13];
  const float* skip1_w = (const float*)d_in[14];
  const float* skip1_b = (const float*)d_in[15];
  const float* skip2_w = (const float*)d_in[16];
  const float* skip2_b = (const float*)d_in[17];
  const float* mlp1_w  = (const float*)d_in[18];
  const float* mlp1_b  = (const float*)d_in[19];
  const float* mlp2_w  = (const float*)d_in[20];
  const float* mlp2_b  = (const float*)d_in[21];

  const int N = in_sizes[0] / 128;
  const int E = in_sizes[1] / 2;
  float* out = (float*)d_out;

  char* ws = (char*)d_ws;
  size_t off = 0;
  auto alloc = [&](size_t bytes) -> void* {
    void* p = ws + off;
    off = (off + bytes + 255) & ~(size_t)255;
    return p;
  };
  int* rowptr  = (int*)alloc((size_t)(N + 1) * sizeof(int));
  int* cnt     = (int*)alloc((size_t)N * sizeof(int));
  int* tscan   = (int*)alloc((size_t)N * sizeof(int));
  int* bsum    = (int*)alloc((size_t)1024 * sizeof(int));
  int* csr_src = (int*)alloc((size_t)(E + N) * sizeof(int));
  ushort* wpk[8];
  for (int i = 0; i < 8; ++i) wpk[i] = (ushort*)alloc(128 * 128 * 2 * sizeof(ushort));
  ushort* p0hi = (ushort*)alloc((size_t)N * 128 * sizeof(ushort));
  ushort* p0lo = (ushort*)alloc((size_t)N * 128 * sizeof(ushort));
  ushort* xlb  = (ushort*)alloc((size_t)N * 128 * sizeof(ushort));
  ushort* xrb  = (ushort*)alloc((size_t)N * 128 * sizeof(ushort));
  float* bufC  = (float*)alloc((size_t)N * 128 * sizeof(float));

  const int* srcp = ei;
  const int* dstp = ei + E;

  const int egrid = (E + 255) / 256;
  const int ggrid = (N + 63) / 64;
  const int agrid = (N + 3) / 4;
  const int nb = (N + 1023) / 1024;

  // CSR by dst with embedded self-loops (5 launches)
  hipMemsetAsync(cnt, 0, (size_t)N * sizeof(int), stream);
  count_kernel<<<egrid, 256, 0, stream>>>(dstp, cnt, E);
  scan_blocks<<<nb, 1024, 0, stream>>>(cnt, tscan, bsum, N);
  scan_final<<<nb, 1024, 0, stream>>>(cnt, tscan, bsum, rowptr, csr_src, N, nb);
  fill_kernel<<<egrid, 256, 0, stream>>>(srcp, dstp, rowptr, cnt, csr_src, E);

  // Weight packs (one launch) + x split
  PackArgs pa;
  pa.w[0] = Wl1;    pa.o[0] = wpk[0]; pa.nout[0] = 128;
  pa.w[1] = Wr1;    pa.o[1] = wpk[1]; pa.nout[1] = 128;
  pa.w[2] = skip1_w;pa.o[2] = wpk[2]; pa.nout[2] = 128;
  pa.w[3] = Wl2;    pa.o[3] = wpk[3]; pa.nout[3] = 128;
  pa.w[4] = Wr2;    pa.o[4] = wpk[4]; pa.nout[4] = 128;
  pa.w[5] = skip2_w;pa.o[5] = wpk[5]; pa.nout[5] = 128;
  pa.w[6] = mlp1_w; pa.o[6] = wpk[6]; pa.nout[6] = 128;
  pa.w[7] = mlp2_w; pa.o[7] = wpk[7]; pa.nout[7] = 64;
  pack_all<<<64, 256, 0, stream>>>(pa);
  split_f32<<<(N * 128 / 4 + 255) / 256, 256, 0, stream>>>(x, p0hi, p0lo, N * 128);

  // ---- Layer 1: fused {xl1, xr1 (bf16), skip1} GEMM, then agg ----
  gemm3_mfma<<<ggrid, 512, 0, stream>>>(p0hi, p0lo, wpk[0], wpk[1], wpk[2],
                                        bl1, br1, skip1_b, xlb, xrb, bufC, N);
  gat_agg<4, true><<<agrid, 256, 0, stream>>>(xlb, xrb, bufC, att1, b1,
                                              rowptr, csr_src, nullptr, p0hi, p0lo, N, 1);

  // ---- Layer 2: fused {xl2, xr2 (bf16), skip2} GEMM, then agg ----
  gemm3_mfma<<<ggrid, 512, 0, stream>>>(p0hi, p0lo, wpk[3], wpk[4], wpk[5],
                                        bl2, br2, skip2_b, xlb, xrb, bufC, N);
  gat_agg<1, true><<<agrid, 256, 0, stream>>>(xlb, xrb, bufC, att2, b2,
                                              rowptr, csr_src, nullptr, p0hi, p0lo, N, 0);

  // ---- Fused MLP head ----
  mlp_fused<<<ggrid, 256, 0, stream>>>(p0hi, p0lo, wpk[6], mlp1_b, wpk[7], mlp2_b, out, N);
}

// Round 11
// 552.037 us; speedup vs baseline: 1.6203x; 1.0701x over previous
//
#include <hip/hip_runtime.h>

#define LEAK 0.2f

typedef __attribute__((ext_vector_type(8))) short short8v;
typedef __attribute__((ext_vector_type(4))) float float4v;

__device__ __forceinline__ ushort f2bf(float f) {
  union { float f; unsigned u; } v; v.f = f;
  unsigned r = v.u + 0x7fffu + ((v.u >> 16) & 1u);  // RNE
  return (ushort)(r >> 16);
}
__device__ __forceinline__ float bf2f(ushort h) {
  union { unsigned u; float f; } v; v.u = ((unsigned)h) << 16;
  return v.f;
}
// leaky_relu(t, 0.2) = 0.6t + 0.4|t|  (2 VALU: mul + fma-with-abs)
__device__ __forceinline__ float lrelu(float t) {
  return fmaf(0.4f, fabsf(t), 0.6f * t);
}

// ---------------- CSR build (incoming edges per dst, self-loop appended) ----------------
// Partitioned by dst range into 8 block-groups (blockIdx&7 ~ XCD with round-robin
// dispatch): each group's cnt-atomics / csr_src-writes hit a contiguous 1/8 slice
// that stays in ONE XCD's L2 -> dense line write-back (fixes the 16x write
// amplification measured in r10: WRITE_SIZE 106MB for 6.4MB of payload).
__global__ void count_part(const int* __restrict__ dstp, int* __restrict__ cnt,
                           int E, int N, int nblk) {
  int grp = blockIdx.x & 7;
  int gb = blockIdx.x >> 3;
  int gn = nblk >> 3;
  int lo = (int)(((long long)N * grp) >> 3);
  int hi = (int)(((long long)N * (grp + 1)) >> 3);
  for (int e = gb * blockDim.x + threadIdx.x; e < E; e += gn * blockDim.x) {
    int d = dstp[e];
    if (d >= lo && d < hi) atomicAdd(&cnt[d], 1);
  }
}

__global__ void fill_part(const int* __restrict__ srcp, const int* __restrict__ dstp,
                          const int* __restrict__ rowptr, int* __restrict__ cur,
                          int* __restrict__ csr_src, int E, int N, int nblk) {
  int grp = blockIdx.x & 7;
  int gb = blockIdx.x >> 3;
  int gn = nblk >> 3;
  int lo = (int)(((long long)N * grp) >> 3);
  int hi = (int)(((long long)N * (grp + 1)) >> 3);
  for (int e = gb * blockDim.x + threadIdx.x; e < E; e += gn * blockDim.x) {
    int d = dstp[e];
    if (d >= lo && d < hi) {
      int pos = atomicAdd(&cur[d], 1);
      csr_src[rowptr[d] + pos] = srcp[e];
    }
  }
}

// per-1024-block inclusive scan over (cnt[i]+1); raw block sums to bsum
__global__ __launch_bounds__(1024)
void scan_blocks(const int* __restrict__ cnt, int* __restrict__ tscan,
                 int* __restrict__ bsum, int n) {
  __shared__ int sh[1024];
  int t = threadIdx.x;
  int i = blockIdx.x * 1024 + t;
  sh[t] = (i < n) ? cnt[i] + 1 : 0;
  __syncthreads();
  for (int off = 1; off < 1024; off <<= 1) {
    int u = (t >= off) ? sh[t - off] : 0;
    __syncthreads();
    sh[t] += u;
    __syncthreads();
  }
  if (i < n) tscan[i] = sh[t];
  if (t == 1023) bsum[blockIdx.x] = sh[1023];
}

// fused: local scan of raw bsum + rowptr + self-loop slot + cur-zeroing + total
__global__ __launch_bounds__(1024)
void scan_final(int* __restrict__ cnt, const int* __restrict__ tscan,
                const int* __restrict__ bsum, int* __restrict__ rowptr,
                int* __restrict__ csr_src, int n, int nb) {
  __shared__ int sh[1024];
  int t = threadIdx.x;
  sh[t] = (t < nb) ? bsum[t] : 0;
  __syncthreads();
  for (int off = 1; off < 1024; off <<= 1) {
    int u = (t >= off) ? sh[t - off] : 0;
    __syncthreads();
    sh[t] += u;
    __syncthreads();
  }
  int i = blockIdx.x * 1024 + t;
  if (i < n) {
    int bpref = (blockIdx.x == 0) ? 0 : sh[blockIdx.x - 1];
    int incl = bpref + tscan[i];          // inclusive scan of (cnt+1)
    rowptr[i] = incl - (cnt[i] + 1);
    csr_src[incl - 1] = i;                // self-loop in node's LAST slot
    cnt[i] = 0;                           // becomes `cur` for fill_part
  }
  if (blockIdx.x == nb - 1 && t == 0) rowptr[n] = sh[nb - 1];
}

// ---------------- bf16 split helpers ----------------
__global__ void split_f32(const float* __restrict__ a, ushort* __restrict__ hi,
                          ushort* __restrict__ lo, int n) {
  int i = (blockIdx.x * blockDim.x + threadIdx.x) * 4;
  if (i >= n) return;
  float4 v = *(const float4*)(a + i);
  ushort h[4], l[4];
  float vv[4] = {v.x, v.y, v.z, v.w};
#pragma unroll
  for (int j = 0; j < 4; ++j) {
    h[j] = f2bf(vv[j]);
    l[j] = f2bf(vv[j] - bf2f(h[j]));
  }
  *(ushort4*)(hi + i) = make_ushort4(h[0], h[1], h[2], h[3]);
  *(ushort4*)(lo + i) = make_ushort4(l[0], l[1], l[2], l[3]);
}

// Pack all 8 weight matrices in ONE launch.
struct PackArgs {
  const float* w[8];
  ushort* o[8];
  int nout[8];
};
__global__ __launch_bounds__(256)
void pack_all(PackArgs pa) {
  int wsel = blockIdx.x >> 3;
  int sub = blockIdx.x & 7;
  const float* W = pa.w[wsel];
  ushort* pk = pa.o[wsel];
  int NOUT = pa.nout[wsel];
  int NT = NOUT / 16;
  int total = NT * 4 * 64;
  int t = sub * 256 + threadIdx.x;
  if (t >= total) return;
  int lane = t & 63;
  int ks = (t >> 6) & 3;
  int nt = t >> 8;
  int col = nt * 16 + (lane & 15);
  int k0 = ks * 32 + (lane >> 4) * 8;
  ushort h[8], l[8];
#pragma unroll
  for (int j = 0; j < 8; ++j) {
    float v = W[(size_t)(k0 + j) * NOUT + col];
    h[j] = f2bf(v);
    l[j] = f2bf(v - bf2f(h[j]));
  }
  size_t fb = ((size_t)(nt * 4 + ks) * 64 + lane) * 8;
  size_t fragsz = (size_t)total * 8;
#pragma unroll
  for (int j = 0; j < 8; ++j) { pk[fb + j] = h[j]; pk[fragsz + fb + j] = l[j]; }
}

// ---------- Fused triple MFMA GEMM: C0,C1 bf16; C2 fp32 ----------
__global__ __launch_bounds__(512)
void gemm3_mfma(const ushort* __restrict__ Ahi, const ushort* __restrict__ Alo,
                const ushort* __restrict__ W0, const ushort* __restrict__ W1,
                const ushort* __restrict__ W2,
                const float* __restrict__ b0, const float* __restrict__ b1,
                const float* __restrict__ b2,
                ushort* __restrict__ C0b, ushort* __restrict__ C1b,
                float* __restrict__ C2, int M) {
  int tid = threadIdx.x;
  int w = tid >> 6, lane = tid & 63;
  int l15 = lane & 15, lh = lane >> 4;
  int row0 = blockIdx.x * 64;

  const ushort* Wp[3] = {W0, W1, W2};

  int arow[4];
#pragma unroll
  for (int mt = 0; mt < 4; ++mt) { int rr = row0 + mt * 16 + l15; arow[mt] = rr < M ? rr : M - 1; }

  float4v acc[3][4];
#pragma unroll
  for (int p = 0; p < 3; ++p)
#pragma unroll
    for (int mt = 0; mt < 4; ++mt) {
      acc[p][mt][0] = 0.f; acc[p][mt][1] = 0.f; acc[p][mt][2] = 0.f; acc[p][mt][3] = 0.f;
    }

  const size_t fragsz = (size_t)8 * 4 * 64 * 8;  // NT=8
#pragma unroll 1
  for (int ks = 0; ks < 4; ++ks) {
    short8v bh[3], bl[3];
    size_t fb = ((size_t)(w * 4 + ks) * 64 + lane) * 8;
#pragma unroll
    for (int p = 0; p < 3; ++p) {
      bh[p] = *(const short8v*)(Wp[p] + fb);
      bl[p] = *(const short8v*)(Wp[p] + fragsz + fb);
    }
#pragma unroll
    for (int mt = 0; mt < 4; ++mt) {
      size_t ao = (size_t)arow[mt] * 128 + ks * 32 + lh * 8;
      short8v ah = *(const short8v*)(Ahi + ao);
      short8v al = *(const short8v*)(Alo + ao);
#pragma unroll
      for (int p = 0; p < 3; ++p) {
        acc[p][mt] = __builtin_amdgcn_mfma_f32_16x16x32_bf16(ah, bh[p], acc[p][mt], 0, 0, 0);
        acc[p][mt] = __builtin_amdgcn_mfma_f32_16x16x32_bf16(ah, bl[p], acc[p][mt], 0, 0, 0);
        acc[p][mt] = __builtin_amdgcn_mfma_f32_16x16x32_bf16(al, bh[p], acc[p][mt], 0, 0, 0);
      }
    }
  }

  int col = w * 16 + l15;
  float bb0 = b0[col], bb1 = b1[col], bb2 = b2[col];
#pragma unroll
  for (int mt = 0; mt < 4; ++mt) {
#pragma unroll
    for (int r = 0; r < 4; ++r) {
      int rr = row0 + mt * 16 + lh * 4 + r;
      if (rr < M) {
        C0b[(size_t)rr * 128 + col] = f2bf(acc[0][mt][r] + bb0);
        C1b[(size_t)rr * 128 + col] = f2bf(acc[1][mt][r] + bb1);
        C2[(size_t)rr * 128 + col] = acc[2][mt][r] + bb2;
      }
    }
  }
}

// ---------- Fused MLP head: out = relu(A@W1+b1) @ W2 + b2 ----------
__global__ __launch_bounds__(256)
void mlp_fused(const ushort* __restrict__ Ahi, const ushort* __restrict__ Alo,
               const ushort* __restrict__ W1pk, const float* __restrict__ b1,
               const ushort* __restrict__ W2pk, const float* __restrict__ b2,
               float* __restrict__ out, int M) {
  __shared__ ushort m1[2][16][64][8];   // [hi/lo][k>>3][row][k&7]
  int tid = threadIdx.x;
  int w = tid >> 6, lane = tid & 63;
  int l15 = lane & 15, lh = lane >> 4;
  int row0 = blockIdx.x * 64;

  int arow[4];
#pragma unroll
  for (int mt = 0; mt < 4; ++mt) { int rr = row0 + mt * 16 + l15; arow[mt] = rr < M ? rr : M - 1; }

  // ---- stage 1: mlp1 (NT=8, WNT=2) ----
  float4v acc1[4][2];
#pragma unroll
  for (int mt = 0; mt < 4; ++mt)
#pragma unroll
    for (int j = 0; j < 2; ++j) {
      acc1[mt][j][0] = 0.f; acc1[mt][j][1] = 0.f; acc1[mt][j][2] = 0.f; acc1[mt][j][3] = 0.f;
    }
  const size_t fragsz1 = (size_t)8 * 4 * 64 * 8;
#pragma unroll 1
  for (int ks = 0; ks < 4; ++ks) {
    short8v bh[2], bl[2];
#pragma unroll
    for (int nt2 = 0; nt2 < 2; ++nt2) {
      size_t fb = ((size_t)((w * 2 + nt2) * 4 + ks) * 64 + lane) * 8;
      bh[nt2] = *(const short8v*)(W1pk + fb);
      bl[nt2] = *(const short8v*)(W1pk + fragsz1 + fb);
    }
#pragma unroll
    for (int mt = 0; mt < 4; ++mt) {
      size_t ao = (size_t)arow[mt] * 128 + ks * 32 + lh * 8;
      short8v ah = *(const short8v*)(Ahi + ao);
      short8v al = *(const short8v*)(Alo + ao);
#pragma unroll
      for (int nt2 = 0; nt2 < 2; ++nt2) {
        acc1[mt][nt2] = __builtin_amdgcn_mfma_f32_16x16x32_bf16(ah, bh[nt2], acc1[mt][nt2], 0, 0, 0);
        acc1[mt][nt2] = __builtin_amdgcn_mfma_f32_16x16x32_bf16(ah, bl[nt2], acc1[mt][nt2], 0, 0, 0);
        acc1[mt][nt2] = __builtin_amdgcn_mfma_f32_16x16x32_bf16(al, bh[nt2], acc1[mt][nt2], 0, 0, 0);
      }
    }
  }
  // relu + split -> LDS
#pragma unroll
  for (int nt2 = 0; nt2 < 2; ++nt2) {
    int col = (w * 2 + nt2) * 16 + l15;
    float bb = b1[col];
    int kf = col >> 3, kr = col & 7;
#pragma unroll
    for (int mt = 0; mt < 4; ++mt) {
#pragma unroll
      for (int r = 0; r < 4; ++r) {
        int row = mt * 16 + lh * 4 + r;
        float v = fmaxf(acc1[mt][nt2][r] + bb, 0.f);
        ushort h = f2bf(v);
        m1[0][kf][row][kr] = h;
        m1[1][kf][row][kr] = f2bf(v - bf2f(h));
      }
    }
  }
  __syncthreads();

  // ---- stage 2: mlp2 (NT=4, wave w -> nt=w) ----
  float4v acc2[4];
#pragma unroll
  for (int mt = 0; mt < 4; ++mt) {
    acc2[mt][0] = 0.f; acc2[mt][1] = 0.f; acc2[mt][2] = 0.f; acc2[mt][3] = 0.f;
  }
  const size_t fragsz2 = (size_t)4 * 4 * 64 * 8;
#pragma unroll 1
  for (int ks = 0; ks < 4; ++ks) {
    size_t fb = ((size_t)(w * 4 + ks) * 64 + lane) * 8;
    short8v bh = *(const short8v*)(W2pk + fb);
    short8v bl = *(const short8v*)(W2pk + fragsz2 + fb);
#pragma unroll
    for (int mt = 0; mt < 4; ++mt) {
      int row = mt * 16 + l15;
      short8v ah = *(const short8v*)&m1[0][ks * 4 + lh][row][0];
      short8v al = *(const short8v*)&m1[1][ks * 4 + lh][row][0];
      acc2[mt] = __builtin_amdgcn_mfma_f32_16x16x32_bf16(ah, bh, acc2[mt], 0, 0, 0);
      acc2[mt] = __builtin_amdgcn_mfma_f32_16x16x32_bf16(ah, bl, acc2[mt], 0, 0, 0);
      acc2[mt] = __builtin_amdgcn_mfma_f32_16x16x32_bf16(al, bh, acc2[mt], 0, 0, 0);
    }
  }
  int col = w * 16 + l15;
  float bb = b2[col];
#pragma unroll
  for (int mt = 0; mt < 4; ++mt) {
#pragma unroll
    for (int r = 0; r < 4; ++r) {
      int rr = row0 + mt * 16 + lh * 4 + r;
      if (rr < M) out[(size_t)rr * 64 + col] = acc2[mt][r] + bb;
    }
  }
}

// ---------- GATv2 aggregation: one wave per node, 2 edges per wave ----------
template<int H, bool SPLIT>
__global__ __launch_bounds__(256)
void gat_agg(const ushort* __restrict__ xlb, const ushort* __restrict__ xrb,
             const float* __restrict__ skip, const float* __restrict__ att,
             const float* __restrict__ gbias, const int* __restrict__ rowptr,
             const int* __restrict__ csr_src, float* __restrict__ out,
             ushort* __restrict__ outhi, ushort* __restrict__ outlo,
             int n, int relu) {
  constexpr int GL = (128 / H) / 4;  // lanes per head group: H=4 -> 8, H=1 -> 32
  int wid = blockIdx.x * (blockDim.x >> 6) + (threadIdx.x >> 6);
  if (wid >= n) return;
  int lane = threadIdx.x & 63;
  int half = lane >> 5;
  int sub = lane & 31;
  size_t base = (size_t)wid * 128 + sub * 4;
  uint2 ur = *(const uint2*)(xrb + base);
  float4 xrv;
  xrv.x = __uint_as_float(ur.x << 16); xrv.y = __uint_as_float(ur.x & 0xFFFF0000u);
  xrv.z = __uint_as_float(ur.y << 16); xrv.w = __uint_as_float(ur.y & 0xFFFF0000u);
  float4 av = *(const float4*)(att + sub * 4);
  float ax = 0.f, ay = 0.f, az = 0.f, aw = 0.f;
  float denom = 0.f;
  int e0 = rowptr[wid], e1 = rowptr[wid + 1];

  int idx = e0 + half;
  for (; idx + 2 < e1; idx += 4) {
    int s0 = csr_src[idx], s1 = csr_src[idx + 2];
    uint2 u0 = *(const uint2*)(xlb + (size_t)s0 * 128 + sub * 4);
    uint2 u1 = *(const uint2*)(xlb + (size_t)s1 * 128 + sub * 4);
    float4 v0, v1;
    v0.x = __uint_as_float(u0.x << 16); v0.y = __uint_as_float(u0.x & 0xFFFF0000u);
    v0.z = __uint_as_float(u0.y << 16); v0.w = __uint_as_float(u0.y & 0xFFFF0000u);
    v1.x = __uint_as_float(u1.x << 16); v1.y = __uint_as_float(u1.x & 0xFFFF0000u);
    v1.z = __uint_as_float(u1.y << 16); v1.w = __uint_as_float(u1.y & 0xFFFF0000u);
    float p0, p1;
    p0 = lrelu(v0.x + xrv.x) * av.x;
    p0 += lrelu(v0.y + xrv.y) * av.y;
    p0 += lrelu(v0.z + xrv.z) * av.z;
    p0 += lrelu(v0.w + xrv.w) * av.w;
    p1 = lrelu(v1.x + xrv.x) * av.x;
    p1 += lrelu(v1.y + xrv.y) * av.y;
    p1 += lrelu(v1.z + xrv.z) * av.z;
    p1 += lrelu(v1.w + xrv.w) * av.w;
#pragma unroll
    for (int o = 1; o < GL; o <<= 1) {
      p0 += __shfl_xor(p0, o, 64);
      p1 += __shfl_xor(p1, o, 64);
    }
    float w0 = __expf(p0), w1 = __expf(p1);
    denom += w0 + w1;
    ax += w0 * v0.x + w1 * v1.x;
    ay += w0 * v0.y + w1 * v1.y;
    az += w0 * v0.z + w1 * v1.z;
    aw += w0 * v0.w + w1 * v1.w;
  }
  for (; idx < e1; idx += 2) {
    int s0 = csr_src[idx];
    uint2 u0 = *(const uint2*)(xlb + (size_t)s0 * 128 + sub * 4);
    float4 v0;
    v0.x = __uint_as_float(u0.x << 16); v0.y = __uint_as_float(u0.x & 0xFFFF0000u);
    v0.z = __uint_as_float(u0.y << 16); v0.w = __uint_as_float(u0.y & 0xFFFF0000u);
    float p0;
    p0 = lrelu(v0.x + xrv.x) * av.x;
    p0 += lrelu(v0.y + xrv.y) * av.y;
    p0 += lrelu(v0.z + xrv.z) * av.z;
    p0 += lrelu(v0.w + xrv.w) * av.w;
#pragma unroll
    for (int o = 1; o < GL; o <<= 1) p0 += __shfl_xor(p0, o, 64);
    float w0 = __expf(p0);
    denom += w0;
    ax += w0 * v0.x;
    ay += w0 * v0.y;
    az += w0 * v0.z;
    aw += w0 * v0.w;
  }

  // combine the two halves
  ax += __shfl_xor(ax, 32, 64);
  ay += __shfl_xor(ay, 32, 64);
  az += __shfl_xor(az, 32, 64);
  aw += __shfl_xor(aw, 32, 64);
  denom += __shfl_xor(denom, 32, 64);

  if (half == 0) {
    float inv = 1.f / denom;
    float4 sk = *(const float4*)(skip + base);
    float4 gb = *(const float4*)(gbias + sub * 4);
    float o0 = ax * inv + gb.x + sk.x;
    float o1 = ay * inv + gb.y + sk.y;
    float o2 = az * inv + gb.z + sk.z;
    float o3 = aw * inv + gb.w + sk.w;
    if (relu) {
      o0 = fmaxf(o0, 0.f); o1 = fmaxf(o1, 0.f);
      o2 = fmaxf(o2, 0.f); o3 = fmaxf(o3, 0.f);
    }
    if (SPLIT) {
      ushort h0 = f2bf(o0), h1 = f2bf(o1), h2 = f2bf(o2), h3 = f2bf(o3);
      *(ushort4*)(outhi + base) = make_ushort4(h0, h1, h2, h3);
      *(ushort4*)(outlo + base) = make_ushort4(f2bf(o0 - bf2f(h0)), f2bf(o1 - bf2f(h1)),
                                               f2bf(o2 - bf2f(h2)), f2bf(o3 - bf2f(h3)));
    } else {
      *(float4*)(out + base) = make_float4(o0, o1, o2, o3);
    }
  }
}

extern "C" void kernel_launch(void* const* d_in, const int* in_sizes, int n_in,
                              void* d_out, int out_size, void* d_ws, size_t ws_size,
                              hipStream_t stream) {
  const float* x       = (const float*)d_in[0];
  const int* ei        = (const int*)d_in[1];
  const float* Wl1     = (const float*)d_in[2];
  const float* bl1     = (const float*)d_in[3];
  const float* Wr1     = (const float*)d_in[4];
  const float* br1     = (const float*)d_in[5];
  const float* att1    = (const float*)d_in[6];
  const float* b1      = (const float*)d_in[7];
  const float* Wl2     = (const float*)d_in[8];
  const float* bl2     = (const float*)d_in[9];
  const float* Wr2     = (const float*)d_in[10];
  const float* br2     = (const float*)d_in[11];
  const float* att2    = (const float*)d_in[12];
  const float* b2      = (const float*)d_in[13];
  const float* skip1_w = (const float*)d_in[14];
  const float* skip1_b = (const float*)d_in[15];
  const float* skip2_w = (const float*)d_in[16];
  const float* skip2_b = (const float*)d_in[17];
  const float* mlp1_w  = (const float*)d_in[18];
  const float* mlp1_b  = (const float*)d_in[19];
  const float* mlp2_w  = (const float*)d_in[20];
  const float* mlp2_b  = (const float*)d_in[21];

  const int N = in_sizes[0] / 128;
  const int E = in_sizes[1] / 2;
  float* out = (float*)d_out;

  char* ws = (char*)d_ws;
  size_t off = 0;
  auto alloc = [&](size_t bytes) -> void* {
    void* p = ws + off;
    off = (off + bytes + 255) & ~(size_t)255;
    return p;
  };
  int* rowptr  = (int*)alloc((size_t)(N + 1) * sizeof(int));
  int* cnt     = (int*)alloc((size_t)N * sizeof(int));
  int* tscan   = (int*)alloc((size_t)N * sizeof(int));
  int* bsum    = (int*)alloc((size_t)1024 * sizeof(int));
  int* csr_src = (int*)alloc((size_t)(E + N) * sizeof(int));
  ushort* wpk[8];
  for (int i = 0; i < 8; ++i) wpk[i] = (ushort*)alloc(128 * 128 * 2 * sizeof(ushort));
  ushort* p0hi = (ushort*)alloc((size_t)N * 128 * sizeof(ushort));
  ushort* p0lo = (ushort*)alloc((size_t)N * 128 * sizeof(ushort));
  ushort* xlb  = (ushort*)alloc((size_t)N * 128 * sizeof(ushort));
  ushort* xrb  = (ushort*)alloc((size_t)N * 128 * sizeof(ushort));
  float* bufC  = (float*)alloc((size_t)N * 128 * sizeof(float));

  const int* srcp = ei;
  const int* dstp = ei + E;

  const int ggrid = (N + 63) / 64;
  const int agrid = (N + 3) / 4;
  const int nb = (N + 1023) / 1024;
  const int PARTB = 2048;  // multiple of 8; 256 blocks per dst-range group

  // CSR by dst with embedded self-loops (partitioned count/fill)
  hipMemsetAsync(cnt, 0, (size_t)N * sizeof(int), stream);
  count_part<<<PARTB, 256, 0, stream>>>(dstp, cnt, E, N, PARTB);
  scan_blocks<<<nb, 1024, 0, stream>>>(cnt, tscan, bsum, N);
  scan_final<<<nb, 1024, 0, stream>>>(cnt, tscan, bsum, rowptr, csr_src, N, nb);
  fill_part<<<PARTB, 256, 0, stream>>>(srcp, dstp, rowptr, cnt, csr_src, E, N, PARTB);

  // Weight packs (one launch) + x split
  PackArgs pa;
  pa.w[0] = Wl1;    pa.o[0] = wpk[0]; pa.nout[0] = 128;
  pa.w[1] = Wr1;    pa.o[1] = wpk[1]; pa.nout[1] = 128;
  pa.w[2] = skip1_w;pa.o[2] = wpk[2]; pa.nout[2] = 128;
  pa.w[3] = Wl2;    pa.o[3] = wpk[3]; pa.nout[3] = 128;
  pa.w[4] = Wr2;    pa.o[4] = wpk[4]; pa.nout[4] = 128;
  pa.w[5] = skip2_w;pa.o[5] = wpk[5]; pa.nout[5] = 128;
  pa.w[6] = mlp1_w; pa.o[6] = wpk[6]; pa.nout[6] = 128;
  pa.w[7] = mlp2_w; pa.o[7] = wpk[7]; pa.nout[7] = 64;
  pack_all<<<64, 256, 0, stream>>>(pa);
  split_f32<<<(N * 128 / 4 + 255) / 256, 256, 0, stream>>>(x, p0hi, p0lo, N * 128);

  // ---- Layer 1: fused {xl1, xr1 (bf16), skip1} GEMM, then agg ----
  gemm3_mfma<<<ggrid, 512, 0, stream>>>(p0hi, p0lo, wpk[0], wpk[1], wpk[2],
                                        bl1, br1, skip1_b, xlb, xrb, bufC, N);
  gat_agg<4, true><<<agrid, 256, 0, stream>>>(xlb, xrb, bufC, att1, b1,
                                              rowptr, csr_src, nullptr, p0hi, p0lo, N, 1);

  // ---- Layer 2: fused {xl2, xr2 (bf16), skip2} GEMM, then agg ----
  gemm3_mfma<<<ggrid, 512, 0, stream>>>(p0hi, p0lo, wpk[3], wpk[4], wpk[5],
                                        bl2, br2, skip2_b, xlb, xrb, bufC, N);
  gat_agg<1, true><<<agrid, 256, 0, stream>>>(xlb, xrb, bufC, att2, b2,
                                              rowptr, csr_src, nullptr, p0hi, p0lo, N, 0);

  // ---- Fused MLP head ----
  mlp_fused<<<ggrid, 256, 0, stream>>>(p0hi, p0lo, wpk[6], mlp1_b, wpk[7], mlp2_b, out, N);
}